// Round 5
// baseline (3112.186 us; speedup 1.0000x reference)
//
#include <hip/hip_runtime.h>
#include <stdint.h>

// M-RNN bidirectional GRU imputation for MI355X (gfx950).
// B=512, T=128, V=59, H=512. bf16 MFMA + fp32 state in registers.
// R5: wave-asynchronous recurrence. No __syncthreads in the main loop:
//  - A-fragments (h and x) loaded DIRECTLY from global into registers in
//    MFMA fragment layout (16B contiguous per lane) -- no LDS A staging.
//  - each wave (mt,tc) owns batch rows mt*16..+15 of its group stripe; the
//    16-row bands are closed systems across blocks of the same mblk.
//  - sync: per-(mblk,mt,ublk,tc) single-writer slot (64B spaced, MALL ops),
//    per-wave 32-lane ballot poll. No atomics, no block barriers.
//  - h exchange keeps R4's proven path: dual store (sc0 local-L2 + sc0sc1
//    MALL copy), sc0 loads (same-XCD L2 hit, else MALL fill). FETCH stays low.
//  - per-wave vmcnt ledger: issue [h x16][x' x6]; position k waits
//    vmcnt(20-2k); sched_barrier(0) after every wait (compiler fence).
// Weights stay LDS-resident (Bw 96x704 swizzled, 135168 B), one initial sync.

typedef unsigned short ushort_t;
typedef __bf16 bf16x8 __attribute__((ext_vector_type(8)));
typedef float f32x4 __attribute__((ext_vector_type(4)));
typedef unsigned int u32x4 __attribute__((ext_vector_type(4)));

__device__ __forceinline__ ushort_t f2bf(float f) {
    union { float f; uint32_t u; } c; c.f = f;
    uint32_t u = c.u;
    uint32_t r = (u + 0x7FFFu + ((u >> 16) & 1u)) >> 16;
    return (ushort_t)r;
}

// ---- memory helpers (asm so the manual vmcnt ledger stays exact) ---------
__device__ __forceinline__ u32x4 load_b128_cached(const void* p) {
    u32x4 d;
    asm volatile("global_load_dwordx4 %0, %1, off" : "=v"(d) : "v"(p) : "memory");
    return d;
}
__device__ __forceinline__ u32x4 load_b128_l2(const void* p) {   // bypass L1
    u32x4 d;
    asm volatile("global_load_dwordx4 %0, %1, off sc0" : "=v"(d) : "v"(p) : "memory");
    return d;
}
__device__ __forceinline__ void store_b16_l2(void* p, unsigned v) {
    asm volatile("global_store_short %0, %1, off sc0" :: "v"(p), "v"(v) : "memory");
}
__device__ __forceinline__ void store_b16_mall(void* p, unsigned v) {
    asm volatile("global_store_short %0, %1, off sc0 sc1" :: "v"(p), "v"(v) : "memory");
}
__device__ __forceinline__ void store_u32_mall(void* p, unsigned v) {
    asm volatile("global_store_dword %0, %1, off sc0 sc1" :: "v"(p), "v"(v) : "memory");
}

__device__ __forceinline__ float fast_sigmoid(float x) {
    float e = __expf(-x);
    return __builtin_amdgcn_rcpf(1.f + e);
}
__device__ __forceinline__ float fast_tanh(float x) {
    float xc = fminf(fmaxf(x, -15.f), 15.f);
    float e = __expf(-2.f * xc);
    return (1.f - e) * __builtin_amdgcn_rcpf(1.f + e);
}

// ---------------------------------------------------------------------------
// prep_small: sync slots, slot-0 zeros, bf16 weights, post weights
// ---------------------------------------------------------------------------
__global__ void prep_small(const float* __restrict__ Wih, const float* __restrict__ Whh,
                           const float* __restrict__ Wh,
                           const float* __restrict__ Wf, const float* __restrict__ bf_,
                           const float* __restrict__ Wc, const float* __restrict__ bc,
                           const float* __restrict__ Wi, const float* __restrict__ bi,
                           ushort_t* __restrict__ WhhB, ushort_t* __restrict__ WihB,
                           ushort_t* __restrict__ WhpB,
                           ushort_t* __restrict__ hf0, ushort_t* __restrict__ hb0,
                           float* __restrict__ hstate,
                           ushort_t* __restrict__ Wpost1, ushort_t* __restrict__ Wpost2,
                           float* __restrict__ bcP, float* __restrict__ biP,
                           unsigned* __restrict__ bar, float* __restrict__ outp)
{
    long long gid = (long long)blockIdx.x * blockDim.x + threadIdx.x;
    long long stride = (long long)gridDim.x * blockDim.x;

    if (gid == 0) outp[3866624] = 0.f;   // loss accumulator slot
    for (long long i = gid; i < 2048LL * 16; i += stride) bar[i] = 0u;
    for (long long i = gid; i < 1024LL * 512; i += stride) hstate[i] = 0.f;
    for (long long i = gid; i < 512LL * 512; i += stride) { hf0[i] = 0; hb0[i] = 0; }
    for (long long i = gid; i < 1536LL * 512; i += stride) WhhB[i] = f2bf(Whh[i]);
    for (long long i = gid; i < 1536LL * 192; i += stride) {
        int n = (int)(i / 192), c = (int)(i % 192);
        WihB[i] = (c < 177) ? f2bf(Wih[n * 177 + c]) : (ushort_t)0;
    }
    for (long long i = gid; i < 64LL * 1024; i += stride) {
        int n = (int)(i >> 10), k = (int)(i & 1023);
        WhpB[i] = (n < 59) ? f2bf(Wh[n * 1024 + k]) : (ushort_t)0;
    }
    for (long long i = gid; i < 64LL * 192; i += stride) {
        int n = (int)(i / 192), c = (int)(i % 192);
        float w = 0.f;
        if (n < 59) {
            if (c < 59)       w = (c == n) ? 0.f : Wf[n * 59 + c];
            else if (c < 118) w = Wc[n * 118 + (c - 59)];
            else if (c < 177) w = Wc[n * 118 + 59 + (c - 118)];
        }
        Wpost1[i] = f2bf(w);
    }
    for (long long i = gid; i < 64LL * 64; i += stride) {
        int n = (int)(i >> 6), k = (int)(i & 63);
        Wpost2[i] = (n < 59 && k < 59) ? f2bf(Wi[n * 59 + k]) : (ushort_t)0;
    }
    for (long long i = gid; i < 64; i += stride) {
        bcP[i] = (i < 59) ? (bf_[i] + bc[i]) : 0.f;
        biP[i] = (i < 59) ? bi[i] : 0.f;
    }
}

// ---------------------------------------------------------------------------
// prep_panels: xcat_f / xcat_b / pcat, div-free (block = one (b,t) row)
// ---------------------------------------------------------------------------
__global__ __launch_bounds__(192)
void prep_panels(const float* __restrict__ values, const float* __restrict__ masks,
                 const float* __restrict__ deltas_f, const float* __restrict__ deltas_b,
                 ushort_t* __restrict__ xcat_f, ushort_t* __restrict__ xcat_b,
                 ushort_t* __restrict__ pcat)
{
    const int row = blockIdx.x;            // b*128 + t
    const int c = threadIdx.x;             // 0..191
    const int b = row >> 7, t = row & 127;
    const int tr = 127 - t;
    const long long rowr = (long long)b * 128 + tr;

    float vf = 0.f;
    if (c < 59)       vf = values  [(long long)row * 59 + c];
    else if (c < 118) vf = masks   [(long long)row * 59 + (c - 59)];
    else if (c < 177) vf = deltas_f[(long long)row * 59 + (c - 118)];
    xcat_f[((size_t)t * 512 + b) * 192 + c] = (c < 177) ? f2bf(vf) : (ushort_t)0;

    float vb = 0.f;
    if (c < 59)       vb = values  [rowr * 59 + c];
    else if (c < 118) vb = masks   [rowr * 59 + (c - 59)];
    else if (c < 177) vb = deltas_b[(long long)row * 59 + (c - 118)];
    xcat_b[((size_t)t * 512 + b) * 192 + c] = (c < 177) ? f2bf(vb) : (ushort_t)0;

    if (c < 59)
        pcat[(size_t)row * 192 + c] = f2bf(values[(long long)row * 59 + c]);
    else if (c >= 118 && c < 177)
        pcat[(size_t)row * 192 + c] = f2bf(masks[(long long)row * 59 + (c - 118)]);
    else if (c >= 177)
        pcat[(size_t)row * 192 + c] = 0;
}

// ---------------------------------------------------------------------------
// Persistent recurrence (wave-async): 127 GRU steps, both directions.
// 256 blocks x 512 thr, 1 block/CU. h slab layout [t][m:512][u:512] bf16.
// Per wave (mt,tc) per step t:
//   poll 32 band slots >= t (lanes 0-31; vmcnt(0) each probe drains rx too)
//   issue 16 h fragment loads (sc0)            [outstanding 16]
//   x positions 0-2: 18 MFMAs from rx regs
//   issue 6 x(t+1) fragment prefetches         [outstanding 22]
//   h positions 0-7: wait vmcnt(20-2k) + sched_barrier(0), 6 MFMAs each
//   epilogue: gates; dual b16 stores (sc0 + sc0sc1); vmcnt(0);
//   lane0 slot store (sc0sc1) = t+1
// Slots: bar[((mblk*4+mt)*32 + ublk*2+tc) * 16] (64B spacing), single writer,
// monotonic; no atomics; no __syncthreads after weight staging.
// LDS: Bw 96x704 (135168 B) only.
// ---------------------------------------------------------------------------
__global__ __launch_bounds__(512)
void recurrence_kernel(const ushort_t* __restrict__ WhhB, const ushort_t* __restrict__ WihB,
                       const float* __restrict__ bih, const float* __restrict__ bhh,
                       const ushort_t* __restrict__ xcat_f, const ushort_t* __restrict__ xcat_b,
                       ushort_t* __restrict__ hfS, ushort_t* __restrict__ hbS,
                       unsigned* __restrict__ bar)
{
    extern __shared__ char smem_c[];
    ushort_t* Bw = (ushort_t*)smem_c;          // 96 x 704, col-chunk swizzled

    const int tid  = threadIdx.x;
    const int blk  = blockIdx.x;
    const int ublk = blk & 15;
    const int mblk = blk >> 4;
    const int u0   = ublk * 32;
    const bool fwd = (mblk < 8);
    const int rbase = (fwd ? mblk : mblk - 8) * 64;
    const ushort_t* xbase = fwd ? xcat_f : xcat_b;
    ushort_t* hS = fwd ? hfS : hbS;

    // weight preload (cached loads): row g*32+u -> [Whh(512) | Wih(192)]
    for (int i = tid; i < 96 * 88; i += 512) {
        int row = i / 88, q = i - row * 88;
        int g = row >> 5, u = u0 + (row & 31);
        const ushort_t* src = (q < 64)
            ? WhhB + ((size_t)(g * 512 + u)) * 512 + q * 8
            : WihB + ((size_t)(g * 512 + u)) * 192 + (q - 64) * 8;
        int qs = q ^ (row & 7);
        *(u32x4*)&Bw[row * 704 + qs * 8] = *(const u32x4*)src;
    }

    const int lane = tid & 63, wv = tid >> 6;
    const int mt = wv >> 1, tc = wv & 1;
    const int l15 = lane & 15, lhi = lane >> 4;
    const int aSw = l15 & 7;

    const int u = u0 + tc * 16 + l15;
    const float bR  = bih[u] + bhh[u];
    const float bZ  = bih[512 + u] + bhh[512 + u];
    const float bNX = bih[1024 + u];
    const float bNH = bhh[1024 + u];
    asm volatile("" :: "v"(bR), "v"(bZ), "v"(bNX), "v"(bNH));
    asm volatile("s_waitcnt vmcnt(0) lgkmcnt(0)" ::: "memory");
    __syncthreads();   // weights staged (only block-wide sync in this kernel)

    // band sync bookkeeping
    const unsigned bandSlot = (unsigned)(mblk * 4 + mt) * 32u;
    const unsigned* pollp = bar + ((size_t)bandSlot + (unsigned)lane) * 16;
    unsigned* myslot = bar + ((size_t)bandSlot + (unsigned)(ublk * 2 + tc)) * 16;

    f32x4 hreg = {0.f, 0.f, 0.f, 0.f};
    f32x4 zero = {0.f, 0.f, 0.f, 0.f};
    f32x4 accR, accZ, accNX, accNH;

    u32x4 h0a, h0b, h1a, h1b, h2a, h2b, h3a, h3b;
    u32x4 h4a, h4b, h5a, h5b, h6a, h6b, h7a, h7b;
    u32x4 rx0a, rx0b, rx1a, rx1b, rx2a, rx2b;

    // 6 MFMAs for one 64-wide K position; fragments fa (k 0..31), fb (32..63)
    auto mfma6 = [&](u32x4 fa, u32x4 fb, int jb, f32x4& accN) {
        bf16x8 a0 = *(bf16x8*)&fa;
        bf16x8 a1 = *(bf16x8*)&fb;
        {
            int jB = jb + lhi;
            bf16x8 b0 = *(const bf16x8*)&Bw[( 0 + tc * 16 + l15) * 704 + ((jB ^ aSw) * 8)];
            bf16x8 b1 = *(const bf16x8*)&Bw[(32 + tc * 16 + l15) * 704 + ((jB ^ aSw) * 8)];
            bf16x8 b2 = *(const bf16x8*)&Bw[(64 + tc * 16 + l15) * 704 + ((jB ^ aSw) * 8)];
            accR = __builtin_amdgcn_mfma_f32_16x16x32_bf16(a0, b0, accR, 0, 0, 0);
            accZ = __builtin_amdgcn_mfma_f32_16x16x32_bf16(a0, b1, accZ, 0, 0, 0);
            accN = __builtin_amdgcn_mfma_f32_16x16x32_bf16(a0, b2, accN, 0, 0, 0);
        }
        {
            int jB = jb + 4 + lhi;
            bf16x8 b0 = *(const bf16x8*)&Bw[( 0 + tc * 16 + l15) * 704 + ((jB ^ aSw) * 8)];
            bf16x8 b1 = *(const bf16x8*)&Bw[(32 + tc * 16 + l15) * 704 + ((jB ^ aSw) * 8)];
            bf16x8 b2 = *(const bf16x8*)&Bw[(64 + tc * 16 + l15) * 704 + ((jB ^ aSw) * 8)];
            accR = __builtin_amdgcn_mfma_f32_16x16x32_bf16(a1, b0, accR, 0, 0, 0);
            accZ = __builtin_amdgcn_mfma_f32_16x16x32_bf16(a1, b1, accZ, 0, 0, 0);
            accN = __builtin_amdgcn_mfma_f32_16x16x32_bf16(a1, b2, accN, 0, 0, 0);
        }
    };

    // per-lane row bases
    const size_t mrow = (size_t)(rbase + mt * 16 + l15);

    // ---- prologue: x(0) fragment loads, drained ---------------------------
    {
        const ushort_t* xr = xbase + (mrow) * 192 + lhi * 8;
        rx0a = load_b128_cached(xr);        rx0b = load_b128_cached(xr + 32);
        rx1a = load_b128_cached(xr + 64);   rx1b = load_b128_cached(xr + 96);
        rx2a = load_b128_cached(xr + 128);  rx2b = load_b128_cached(xr + 160);
    }
    asm volatile("s_waitcnt vmcnt(0)" ::: "memory");
    __builtin_amdgcn_sched_barrier(0);

#define HPOS(K, WN, JB)                                                       \
    asm volatile("s_waitcnt vmcnt(" #WN ")" ::: "memory");                    \
    __builtin_amdgcn_sched_barrier(0);                                        \
    mfma6(h##K##a, h##K##b, (JB), accNH);

    for (int t = 0; t < 127; ++t) {
        // ---- per-wave band poll: slots >= t (skip t=0) --------------------
        if (t > 0) {
            const unsigned target = (unsigned)t;
            for (;;) {
                unsigned v = 0xFFFFFFFFu;
                if (lane < 32) {
                    asm volatile("global_load_dword %0, %1, off sc0 sc1"
                                 : "=v"(v) : "v"(pollp) : "memory");
                }
                asm volatile("s_waitcnt vmcnt(0)" ::: "memory");
                if (__ballot(v >= target) == ~0ULL) break;
                __builtin_amdgcn_s_sleep(1);
            }
            __builtin_amdgcn_sched_barrier(0);
        }

        // ---- issue 16 h fragment loads (sc0) ------------------------------
        {
            const ushort_t* hr = hS + (size_t)t * 262144 + mrow * 512 + lhi * 8;
            h0a = load_b128_l2(hr);            h0b = load_b128_l2(hr + 32);
            h1a = load_b128_l2(hr + 64);       h1b = load_b128_l2(hr + 96);
            h2a = load_b128_l2(hr + 128);      h2b = load_b128_l2(hr + 160);
            h3a = load_b128_l2(hr + 192);      h3b = load_b128_l2(hr + 224);
            h4a = load_b128_l2(hr + 256);      h4b = load_b128_l2(hr + 288);
            h5a = load_b128_l2(hr + 320);      h5b = load_b128_l2(hr + 352);
            h6a = load_b128_l2(hr + 384);      h6b = load_b128_l2(hr + 416);
            h7a = load_b128_l2(hr + 448);      h7b = load_b128_l2(hr + 480);
        }

        // ---- x positions 0-2 (fragments ready; cover h latency) -----------
        accR = zero; accZ = zero; accNX = zero; accNH = zero;
        mfma6(rx0a, rx0b, 64, accNX);
        mfma6(rx1a, rx1b, 72, accNX);
        mfma6(rx2a, rx2b, 80, accNX);

        // ---- issue x(t+1) fragment prefetch (6 cached loads) --------------
        {
            const ushort_t* xr = xbase + ((size_t)(t + 1) * 512 + mrow) * 192 + lhi * 8;
            rx0a = load_b128_cached(xr);        rx0b = load_b128_cached(xr + 32);
            rx1a = load_b128_cached(xr + 64);   rx1b = load_b128_cached(xr + 96);
            rx2a = load_b128_cached(xr + 128);  rx2b = load_b128_cached(xr + 160);
        }

        // ---- h positions 0-7 (ledger: 16 h + 6 x' -> wait 20-2k) ----------
        HPOS(0, 20,  0)
        HPOS(1, 18,  8)
        HPOS(2, 16, 16)
        HPOS(3, 14, 24)
        HPOS(4, 12, 32)
        HPOS(5, 10, 40)
        HPOS(6,  8, 48)
        HPOS(7,  6, 56)

        // ---- GRU cell epilogue; dual h stores -----------------------------
        {
            ushort_t* hdst = hS + (size_t)(t + 1) * 262144;
            #pragma unroll
            for (int reg = 0; reg < 4; ++reg) {
                float rr = fast_sigmoid(accR[reg] + bR);
                float zz = fast_sigmoid(accZ[reg] + bZ);
                float nn = fast_tanh(accNX[reg] + bNX + rr * (accNH[reg] + bNH));
                float hnew = (1.f - zz) * nn + zz * hreg[reg];
                hreg[reg] = hnew;
                unsigned hb16 = (unsigned)f2bf(hnew);
                ushort_t* dst = hdst + (size_t)(rbase + mt * 16 + lhi * 4 + reg) * 512 + u;
                store_b16_l2(dst, hb16);     // local L2 (fast same-XCD reads)
                store_b16_mall(dst, hb16);   // MALL copy (cross-XCD correctness)
            }
        }
        asm volatile("s_waitcnt vmcnt(0)" ::: "memory");   // h stores + x' drained

        if (lane == 0)
            store_u32_mall(myslot, (unsigned)(t + 1));     // single-writer slot
    }
#undef HPOS
}

// ---------------------------------------------------------------------------
// Fallback step kernel (used only if cooperative launch unavailable)
// ---------------------------------------------------------------------------
__global__ __launch_bounds__(512)
void step_kernel(const ushort_t* __restrict__ hsrcF, const ushort_t* __restrict__ hsrcB,
                 ushort_t* __restrict__ hdstF, ushort_t* __restrict__ hdstB,
                 const ushort_t* __restrict__ xF, const ushort_t* __restrict__ xB,
                 const ushort_t* __restrict__ WhhB, const ushort_t* __restrict__ WihB,
                 const float* __restrict__ bih, const float* __restrict__ bhh,
                 float* __restrict__ hstate)
{
    __shared__ __align__(16) ushort_t As[64 * 64];
    __shared__ __align__(16) ushort_t Bs[96 * 64];

    const int tid  = threadIdx.x;
    const int ublk = blockIdx.x;
    const int mblk = blockIdx.y;
    const int u0   = ublk * 32;
    const bool fwd = (mblk < 8);
    const ushort_t* hsrc = fwd ? hsrcF : hsrcB;
    const ushort_t* xsrc = fwd ? xF : xB;
    ushort_t* hdst = fwd ? hdstF : hdstB;
    const int rbase = (fwd ? mblk : mblk - 8) * 64;

    const int lane = tid & 63, wv = tid >> 6;
    const int mt = wv >> 1, tc = wv & 1;
    const int l15 = lane & 15, lhi = lane >> 4;

    f32x4 zero = {0.f, 0.f, 0.f, 0.f};
    f32x4 accR = zero, accZ = zero, accNH = zero, accNX = zero;
    const int arow = tid >> 3, ac8 = (tid & 7) * 8;

    for (int chunk = 0; chunk < 11; ++chunk) {
        const bool ph1 = (chunk < 8);
        {
            const ushort_t* src = ph1
                ? hsrc + ((size_t)(rbase + arow)) * 512 + chunk * 64 + ac8
                : xsrc + ((size_t)(rbase + arow)) * 192 + (chunk - 8) * 64 + ac8;
            *(uint4*)&As[arow * 64 + ac8] = *(const uint4*)src;
        }
        {
            int rowB = tid >> 3; int c8 = (tid & 7) * 8;
            int g = rowB >> 5; int u = u0 + (rowB & 31);
            const ushort_t* src = ph1
                ? WhhB + ((size_t)(g * 512 + u)) * 512 + chunk * 64 + c8
                : WihB + ((size_t)(g * 512 + u)) * 192 + (chunk - 8) * 64 + c8;
            *(uint4*)&Bs[rowB * 64 + c8] = *(const uint4*)src;
            if (tid < 256) {
                int u2 = tid + 512;
                rowB = u2 >> 3; c8 = (u2 & 7) * 8;
                g = rowB >> 5; u = u0 + (rowB & 31);
                src = ph1
                    ? WhhB + ((size_t)(g * 512 + u)) * 512 + chunk * 64 + c8
                    : WihB + ((size_t)(g * 512 + u)) * 192 + (chunk - 8) * 64 + c8;
                *(uint4*)&Bs[rowB * 64 + c8] = *(const uint4*)src;
            }
        }
        __syncthreads();
        #pragma unroll
        for (int ks = 0; ks < 64; ks += 32) {
            bf16x8 a  = *(const bf16x8*)&As[(mt * 16 + l15) * 64 + ks + lhi * 8];
            bf16x8 b0 = *(const bf16x8*)&Bs[( 0 + tc * 16 + l15) * 64 + ks + lhi * 8];
            bf16x8 b1 = *(const bf16x8*)&Bs[(32 + tc * 16 + l15) * 64 + ks + lhi * 8];
            bf16x8 b2 = *(const bf16x8*)&Bs[(64 + tc * 16 + l15) * 64 + ks + lhi * 8];
            accR = __builtin_amdgcn_mfma_f32_16x16x32_bf16(a, b0, accR, 0, 0, 0);
            accZ = __builtin_amdgcn_mfma_f32_16x16x32_bf16(a, b1, accZ, 0, 0, 0);
            if (ph1) accNH = __builtin_amdgcn_mfma_f32_16x16x32_bf16(a, b2, accNH, 0, 0, 0);
            else     accNX = __builtin_amdgcn_mfma_f32_16x16x32_bf16(a, b2, accNX, 0, 0, 0);
        }
        __syncthreads();
    }

    const int u = u0 + tc * 16 + l15;
    const float bR  = bih[u] + bhh[u];
    const float bZ  = bih[512 + u] + bhh[512 + u];
    const float bNX = bih[1024 + u];
    const float bNH = bhh[1024 + u];
    #pragma unroll
    for (int reg = 0; reg < 4; ++reg) {
        int m = mblk * 64 + mt * 16 + lhi * 4 + reg;
        float r = 1.f / (1.f + __expf(-(accR[reg] + bR)));
        float z = 1.f / (1.f + __expf(-(accZ[reg] + bZ)));
        float n = tanhf(accNX[reg] + bNX + r * (accNH[reg] + bNH));
        size_t idx = (size_t)m * 512 + u;
        float hold = hstate[idx];
        float hnew = (1.f - z) * n + z * hold;
        hstate[idx] = hnew;
        size_t bloc = (size_t)(fwd ? m : m - 512) * 512 + u;
        hdst[bloc] = f2bf(hnew);
    }
}

// ---------------------------------------------------------------------------
// x_v = [hf, hb_rev] @ Wh^T + bh, written as bf16 into pcat cols 59..117
// ---------------------------------------------------------------------------
__global__ __launch_bounds__(256)
void xv_kernel(const ushort_t* __restrict__ hf, const ushort_t* __restrict__ hb,
               const ushort_t* __restrict__ WhpB, const float* __restrict__ bh,
               ushort_t* __restrict__ pcat)
{
    __shared__ __align__(16) ushort_t As[128 * 64];
    __shared__ __align__(16) ushort_t Bs[64 * 64];
    const int b = blockIdx.x;
    const int tid = threadIdx.x;
    const int lane = tid & 63, wv = tid >> 6;
    const int l15 = lane & 15, lhi = lane >> 4;

    f32x4 zero = {0.f, 0.f, 0.f, 0.f};
    f32x4 acc[2][4];
    #pragma unroll
    for (int i = 0; i < 2; ++i)
        #pragma unroll
        for (int j = 0; j < 4; ++j) acc[i][j] = zero;

    for (int chunk = 0; chunk < 16; ++chunk) {
        const bool fw = (chunk < 8);
        #pragma unroll
        for (int s = 0; s < 4; ++s) {
            int unit = tid + s * 256;
            int row = unit >> 3;
            int c8 = (unit & 7) * 8;
            const ushort_t* src = fw
                ? hf + ((size_t)row * 512 + b) * 512 + chunk * 64 + c8
                : hb + ((size_t)(127 - row) * 512 + b) * 512 + (chunk - 8) * 64 + c8;
            *(uint4*)&As[row * 64 + c8] = *(const uint4*)src;
        }
        #pragma unroll
        for (int s = 0; s < 2; ++s) {
            int unit = tid + s * 256;
            int row = unit >> 3;
            int c8 = (unit & 7) * 8;
            *(uint4*)&Bs[row * 64 + c8] =
                *(const uint4*)(WhpB + (size_t)row * 1024 + chunk * 64 + c8);
        }
        __syncthreads();
        #pragma unroll
        for (int ks = 0; ks < 64; ks += 32) {
            bf16x8 bfr[4];
            #pragma unroll
            for (int nt = 0; nt < 4; ++nt)
                bfr[nt] = *(const bf16x8*)&Bs[(nt * 16 + l15) * 64 + ks + lhi * 8];
            #pragma unroll
            for (int mt2 = 0; mt2 < 2; ++mt2) {
                bf16x8 a = *(const bf16x8*)&As[(wv * 32 + mt2 * 16 + l15) * 64 + ks + lhi * 8];
                #pragma unroll
                for (int nt = 0; nt < 4; ++nt)
                    acc[mt2][nt] = __builtin_amdgcn_mfma_f32_16x16x32_bf16(a, bfr[nt], acc[mt2][nt], 0, 0, 0);
            }
        }
        __syncthreads();
    }
    #pragma unroll
    for (int mt2 = 0; mt2 < 2; ++mt2) {
        #pragma unroll
        for (int nt = 0; nt < 4; ++nt) {
            int col = nt * 16 + l15;
            if (col < 59) {
                float bhc = bh[col];
                #pragma unroll
                for (int reg = 0; reg < 4; ++reg) {
                    int t = wv * 32 + mt2 * 16 + lhi * 4 + reg;
                    pcat[((size_t)b * 128 + t) * 192 + 59 + col] = f2bf(acc[mt2][nt][reg] + bhc);
                }
            }
        }
    }
}

// ---------------------------------------------------------------------------
// Fused post: two chained MFMA GEMMs + x_imp + loss partials
// ---------------------------------------------------------------------------
__global__ __launch_bounds__(256)
void post_kernel(const ushort_t* __restrict__ pcat,
                 const ushort_t* __restrict__ Wpost1, const ushort_t* __restrict__ Wpost2,
                 const float* __restrict__ bcP, const float* __restrict__ biP,
                 const float* __restrict__ values, const float* __restrict__ masks,
                 float* __restrict__ out, float* __restrict__ pnum, float* __restrict__ pden)
{
    __shared__ __align__(16) ushort_t A1[64 * 200];
    __shared__ __align__(16) ushort_t B1[64 * 200];
    __shared__ __align__(16) ushort_t B2[64 * 72];

    const int tid = threadIdx.x;
    const int blk = blockIdx.x;
    const int lane = tid & 63, wv = tid >> 6;
    const int l15 = lane & 15, lhi = lane >> 4;

    #pragma unroll
    for (int s = 0; s < 6; ++s) {
        int unit = tid + s * 256;
        int row = unit / 24, c8 = (unit % 24) * 8;
        *(uint4*)&A1[row * 200 + c8] =
            *(const uint4*)(pcat + ((size_t)blk * 64 + row) * 192 + c8);
        *(uint4*)&B1[row * 200 + c8] =
            *(const uint4*)(Wpost1 + (size_t)row * 192 + c8);
    }
    #pragma unroll
    for (int s = 0; s < 2; ++s) {
        int unit = tid + s * 256;
        int row = unit >> 3, c8 = (unit & 7) * 8;
        *(uint4*)&B2[row * 72 + c8] = *(const uint4*)(Wpost2 + (size_t)row * 64 + c8);
    }
    __syncthreads();

    f32x4 zero = {0.f, 0.f, 0.f, 0.f};
    f32x4 acc1[4];
    #pragma unroll
    for (int nt = 0; nt < 4; ++nt) acc1[nt] = zero;

    #pragma unroll
    for (int ks = 0; ks < 192; ks += 32) {
        bf16x8 a = *(const bf16x8*)&A1[(wv * 16 + l15) * 200 + ks + lhi * 8];
        #pragma unroll
        for (int nt = 0; nt < 4; ++nt) {
            bf16x8 bb = *(const bf16x8*)&B1[(nt * 16 + l15) * 200 + ks + lhi * 8];
            acc1[nt] = __builtin_amdgcn_mfma_f32_16x16x32_bf16(a, bb, acc1[nt], 0, 0, 0);
        }
    }
    __syncthreads();

    #pragma unroll
    for (int nt = 0; nt < 4; ++nt) {
        int col = nt * 16 + l15;
        float bcv = bcP[col];
        #pragma unroll
        for (int reg = 0; reg < 4; ++reg) {
            int row = wv * 16 + lhi * 4 + reg;
            A1[row * 72 + col] = f2bf(acc1[nt][reg] + bcv);
        }
    }
    __syncthreads();

    f32x4 acc2[4];
    #pragma unroll
    for (int nt = 0; nt < 4; ++nt) acc2[nt] = zero;
    #pragma unroll
    for (int ks = 0; ks < 64; ks += 32) {
        bf16x8 a = *(const bf16x8*)&A1[(wv * 16 + l15) * 72 + ks + lhi * 8];
        #pragma unroll
        for (int nt = 0; nt < 4; ++nt) {
            bf16x8 bb = *(const bf16x8*)&B2[(nt * 16 + l15) * 72 + ks + lhi * 8];
            acc2[nt] = __builtin_amdgcn_mfma_f32_16x16x32_bf16(a, bb, acc2[nt], 0, 0, 0);
        }
    }

    float biR[4];
    #pragma unroll
    for (int nt = 0; nt < 4; ++nt) biR[nt] = biP[nt * 16 + l15];

    #pragma unroll
    for (int reg = 0; reg < 4; ++reg) {
        size_t rowg = (size_t)blk * 64 + wv * 16 + lhi * 4 + reg;
        float esum = 0.f, dsum = 0.f;
        #pragma unroll
        for (int nt = 0; nt < 4; ++nt) {
            int col = nt * 16 + l15;
            if (col < 59) {
                float imp = acc2[nt][reg] + biR[nt];
                float v = values[rowg * 59 + col];
                float m = masks [rowg * 59 + col];
                out[rowg * 59 + col] = m * v + (1.f - m) * imp;
                esum += fabsf(v - imp) * m;
                dsum += m;
            }
        }
        #pragma unroll
        for (int o = 1; o < 16; o <<= 1) {
            esum += __shfl_xor(esum, o);
            dsum += __shfl_xor(dsum, o);
        }
        if (l15 == 0) { pnum[rowg] = esum; pden[rowg] = dsum; }
    }
}

// ---------------------------------------------------------------------------
// loss reduction (parallel): block t sums over b, atomicAdd num/(den+eps)
// ---------------------------------------------------------------------------
__global__ __launch_bounds__(256)
void loss_kernel(const float* __restrict__ pnum, const float* __restrict__ pden,
                 float* __restrict__ out)
{
    __shared__ float sn[4], sd[4];
    const int t = blockIdx.x;              // 0..127
    const int tid = threadIdx.x;
    float a = 0.f, b = 0.f;
    for (int bb = tid; bb < 512; bb += 256) {
        a += pnum[(size_t)bb * 128 + t];
        b += pden[(size_t)bb * 128 + t];
    }
    #pragma unroll
    for (int o = 32; o >= 1; o >>= 1) {
        a += __shfl_xor(a, o);
        b += __shfl_xor(b, o);
    }
    const int wv = tid >> 6;
    if ((tid & 63) == 0) { sn[wv] = a; sd[wv] = b; }
    __syncthreads();
    if (tid == 0) {
        float A = sn[0] + sn[1] + sn[2] + sn[3];
        float B = sd[0] + sd[1] + sd[2] + sd[3];
        atomicAdd(out + 3866624, A / (B + 1e-5f));   // B*T*V slot, zeroed by prep
    }
}

// ---------------------------------------------------------------------------
extern "C" void kernel_launch(void* const* d_in, const int* in_sizes, int n_in,
                              void* d_out, int out_size, void* d_ws, size_t ws_size,
                              hipStream_t stream)
{
    const float* values   = (const float*)d_in[0];
    const float* masks    = (const float*)d_in[1];
    const float* deltas_f = (const float*)d_in[2];
    const float* deltas_b = (const float*)d_in[3];
    const float* Wih = (const float*)d_in[4];
    const float* Whh = (const float*)d_in[5];
    const float* bih = (const float*)d_in[6];
    const float* bhh = (const float*)d_in[7];
    const float* Wh  = (const float*)d_in[8];
    const float* bh  = (const float*)d_in[9];
    const float* Wf  = (const float*)d_in[10];
    const float* bf_ = (const float*)d_in[11];
    const float* Wc  = (const float*)d_in[12];
    const float* bc  = (const float*)d_in[13];
    const float* Wi  = (const float*)d_in[14];
    const float* bi  = (const float*)d_in[15];
    float* out = (float*)d_out;

    uint8_t* ws = (uint8_t*)d_ws;
    size_t off = 0;
    auto alloc = [&](size_t bytes) -> void* {
        void* p = ws + off;
        off = (off + bytes + 255) & ~((size_t)255);
        return p;
    };
    ushort_t* xcat_f = (ushort_t*)alloc(128ULL * 512 * 192 * 2);
    ushort_t* xcat_b = (ushort_t*)alloc(128ULL * 512 * 192 * 2);
    ushort_t* WhhB   = (ushort_t*)alloc(1536ULL * 512 * 2);
    ushort_t* WihB   = (ushort_t*)alloc(1536ULL * 192 * 2);
    ushort_t* WhpB   = (ushort_t*)alloc(64ULL * 1024 * 2);
    ushort_t* hfS    = (ushort_t*)alloc(128ULL * 512 * 512 * 2);
    ushort_t* hbS    = (ushort_t*)alloc(128ULL * 512 * 512 * 2);
    float*    hstate = (float*)alloc(1024ULL * 512 * 4);
    ushort_t* pcat   = (ushort_t*)alloc(65536ULL * 192 * 2);
    ushort_t* Wpost1 = (ushort_t*)alloc(64ULL * 192 * 2);
    ushort_t* Wpost2 = (ushort_t*)alloc(64ULL * 64 * 2);
    float*    bcP    = (float*)alloc(64 * 4);
    float*    biP    = (float*)alloc(64 * 4);
    float*    pnum   = (float*)alloc(65536ULL * 4);
    float*    pden   = (float*)alloc(65536ULL * 4);
    unsigned* bar    = (unsigned*)alloc(2048ULL * 16 * 4);   // 128 KB slots

    prep_small<<<1024, 256, 0, stream>>>(Wih, Whh, Wh, Wf, bf_, Wc, bc, Wi, bi,
                                         WhhB, WihB, WhpB, hfS, hbS, hstate,
                                         Wpost1, Wpost2, bcP, biP, bar, out);
    prep_panels<<<65536, 192, 0, stream>>>(values, masks, deltas_f, deltas_b,
                                           xcat_f, xcat_b, pcat);

    // Persistent recurrence (wave-async); fallback: 127 step launches
    const unsigned smemBytes = 96u * 704u * 2u;   // 135168 B (Bw only)
    hipError_t aerr = hipFuncSetAttribute((const void*)recurrence_kernel,
                                          hipFuncAttributeMaxDynamicSharedMemorySize,
                                          (int)smemBytes);
    hipError_t lerr = hipErrorUnknown;
    if (aerr == hipSuccess) {
        const ushort_t* a0 = WhhB; const ushort_t* a1 = WihB;
        const float* a2 = bih; const float* a3 = bhh;
        const ushort_t* a4 = xcat_f; const ushort_t* a5 = xcat_b;
        ushort_t* a6 = hfS; ushort_t* a7 = hbS;
        unsigned* a8 = bar;
        void* args[] = { &a0, &a1, &a2, &a3, &a4, &a5, &a6, &a7, &a8 };
        lerr = hipLaunchCooperativeKernel((const void*)recurrence_kernel,
                                          dim3(256), dim3(512), args, smemBytes, stream);
    }
    if (lerr != hipSuccess) {
        for (int t = 0; t < 127; ++t) {
            step_kernel<<<dim3(16, 16), 512, 0, stream>>>(
                hfS + (size_t)t * 512 * 512, hbS + (size_t)t * 512 * 512,
                hfS + (size_t)(t + 1) * 512 * 512, hbS + (size_t)(t + 1) * 512 * 512,
                xcat_f + (size_t)t * 512 * 192, xcat_b + (size_t)t * 512 * 192,
                WhhB, WihB, bih, bhh, hstate);
        }
    }

    xv_kernel<<<512, 256, 0, stream>>>(hfS, hbS, WhpB, bh, pcat);
    post_kernel<<<1024, 256, 0, stream>>>(pcat, Wpost1, Wpost2, bcP, biP,
                                          values, masks, out, pnum, pden);
    loss_kernel<<<128, 256, 0, stream>>>(pnum, pden, out);
}

// Round 6
// 2934.875 us; speedup vs baseline: 1.0604x; 1.0604x over previous
//
#include <hip/hip_runtime.h>
#include <stdint.h>

// M-RNN bidirectional GRU imputation for MI355X (gfx950).
// B=512, T=128, V=59, H=512. bf16 MFMA + fp32 state in registers.
// R6 = R3's proven lockstep control structure (depth-5 spread h ring,
// atomicAdd+poll group barrier, LDS A-staging) combined with R4's proven
// memory path for the h exchange:
//   - h slab layout [t][p:16][m:512][c:32]: every 128B line belongs to ONE
//     producer block (2 m-rows of one p) -> partial-line stores are sound.
//   - dual h stores from epilogue regs: sc0 (local-L2 dirty, fast same-XCD
//     reads) + sc0 sc1 (MALL copy, cross-XCD correctness).
//   - h loads sc0: same-XCD L2 hit, else MALL fill. (R4 measured: FETCH
//     719->98 MB with this path, absmax clean.)
//   - blockIdx remap: group members congruent mod 8 -> same XCD under
//     round-robin dispatch (heuristic only; correctness never depends on it).

typedef unsigned short ushort_t;
typedef __bf16 bf16x8 __attribute__((ext_vector_type(8)));
typedef float f32x4 __attribute__((ext_vector_type(4)));
typedef unsigned int u32x4 __attribute__((ext_vector_type(4)));

__device__ __forceinline__ ushort_t f2bf(float f) {
    union { float f; uint32_t u; } c; c.f = f;
    uint32_t u = c.u;
    uint32_t r = (u + 0x7FFFu + ((u >> 16) & 1u)) >> 16;
    return (ushort_t)r;
}

// ---- memory helpers (asm so manual vmcnt counting stays exact) -----------
__device__ __forceinline__ u32x4 load_b128_cached(const void* p) {
    u32x4 d;
    asm volatile("global_load_dwordx4 %0, %1, off" : "=v"(d) : "v"(p) : "memory");
    return d;
}
__device__ __forceinline__ u32x4 load_b128_l2(const void* p) {   // bypass L1
    u32x4 d;
    asm volatile("global_load_dwordx4 %0, %1, off sc0" : "=v"(d) : "v"(p) : "memory");
    return d;
}
__device__ __forceinline__ void store_b16_l2(void* p, unsigned v) {
    asm volatile("global_store_short %0, %1, off sc0" :: "v"(p), "v"(v) : "memory");
}
__device__ __forceinline__ void store_b16_mall(void* p, unsigned v) {
    asm volatile("global_store_short %0, %1, off sc0 sc1" :: "v"(p), "v"(v) : "memory");
}

__device__ __forceinline__ float fast_sigmoid(float x) {
    float e = __expf(-x);
    return __builtin_amdgcn_rcpf(1.f + e);
}
__device__ __forceinline__ float fast_tanh(float x) {
    float xc = fminf(fmaxf(x, -15.f), 15.f);
    float e = __expf(-2.f * xc);
    return (1.f - e) * __builtin_amdgcn_rcpf(1.f + e);
}

// ---------------------------------------------------------------------------
// prep_small: barrier counters, slot-0 zeros, bf16 weights, post weights
// ---------------------------------------------------------------------------
__global__ void prep_small(const float* __restrict__ Wih, const float* __restrict__ Whh,
                           const float* __restrict__ Wh,
                           const float* __restrict__ Wf, const float* __restrict__ bf_,
                           const float* __restrict__ Wc, const float* __restrict__ bc,
                           const float* __restrict__ Wi, const float* __restrict__ bi,
                           ushort_t* __restrict__ WhhB, ushort_t* __restrict__ WihB,
                           ushort_t* __restrict__ WhpB,
                           ushort_t* __restrict__ hf0, ushort_t* __restrict__ hb0,
                           float* __restrict__ hstate,
                           ushort_t* __restrict__ Wpost1, ushort_t* __restrict__ Wpost2,
                           float* __restrict__ bcP, float* __restrict__ biP,
                           unsigned* __restrict__ bar, float* __restrict__ outp)
{
    long long gid = (long long)blockIdx.x * blockDim.x + threadIdx.x;
    long long stride = (long long)gridDim.x * blockDim.x;

    if (gid == 0) outp[3866624] = 0.f;   // loss accumulator slot
    for (long long i = gid; i < 16 * 64; i += stride) bar[i] = 0u;
    for (long long i = gid; i < 1024LL * 512; i += stride) hstate[i] = 0.f;
    for (long long i = gid; i < 512LL * 512; i += stride) { hf0[i] = 0; hb0[i] = 0; }
    for (long long i = gid; i < 1536LL * 512; i += stride) WhhB[i] = f2bf(Whh[i]);
    for (long long i = gid; i < 1536LL * 192; i += stride) {
        int n = (int)(i / 192), c = (int)(i % 192);
        WihB[i] = (c < 177) ? f2bf(Wih[n * 177 + c]) : (ushort_t)0;
    }
    for (long long i = gid; i < 64LL * 1024; i += stride) {
        int n = (int)(i >> 10), k = (int)(i & 1023);
        WhpB[i] = (n < 59) ? f2bf(Wh[n * 1024 + k]) : (ushort_t)0;
    }
    for (long long i = gid; i < 64LL * 192; i += stride) {
        int n = (int)(i / 192), c = (int)(i % 192);
        float w = 0.f;
        if (n < 59) {
            if (c < 59)       w = (c == n) ? 0.f : Wf[n * 59 + c];
            else if (c < 118) w = Wc[n * 118 + (c - 59)];
            else if (c < 177) w = Wc[n * 118 + 59 + (c - 118)];
        }
        Wpost1[i] = f2bf(w);
    }
    for (long long i = gid; i < 64LL * 64; i += stride) {
        int n = (int)(i >> 6), k = (int)(i & 63);
        Wpost2[i] = (n < 59 && k < 59) ? f2bf(Wi[n * 59 + k]) : (ushort_t)0;
    }
    for (long long i = gid; i < 64; i += stride) {
        bcP[i] = (i < 59) ? (bf_[i] + bc[i]) : 0.f;
        biP[i] = (i < 59) ? bi[i] : 0.f;
    }
}

// ---------------------------------------------------------------------------
// prep_panels: xcat_f / xcat_b / pcat, div-free (block = one (b,t) row)
// ---------------------------------------------------------------------------
__global__ __launch_bounds__(192)
void prep_panels(const float* __restrict__ values, const float* __restrict__ masks,
                 const float* __restrict__ deltas_f, const float* __restrict__ deltas_b,
                 ushort_t* __restrict__ xcat_f, ushort_t* __restrict__ xcat_b,
                 ushort_t* __restrict__ pcat)
{
    const int row = blockIdx.x;            // b*128 + t
    const int c = threadIdx.x;             // 0..191
    const int b = row >> 7, t = row & 127;
    const int tr = 127 - t;
    const long long rowr = (long long)b * 128 + tr;

    float vf = 0.f;
    if (c < 59)       vf = values  [(long long)row * 59 + c];
    else if (c < 118) vf = masks   [(long long)row * 59 + (c - 59)];
    else if (c < 177) vf = deltas_f[(long long)row * 59 + (c - 118)];
    xcat_f[((size_t)t * 512 + b) * 192 + c] = (c < 177) ? f2bf(vf) : (ushort_t)0;

    float vb = 0.f;
    if (c < 59)       vb = values  [rowr * 59 + c];
    else if (c < 118) vb = masks   [rowr * 59 + (c - 59)];
    else if (c < 177) vb = deltas_b[(long long)row * 59 + (c - 118)];
    xcat_b[((size_t)t * 512 + b) * 192 + c] = (c < 177) ? f2bf(vb) : (ushort_t)0;

    if (c < 59)
        pcat[(size_t)row * 192 + c] = f2bf(values[(long long)row * 59 + c]);
    else if (c >= 118 && c < 177)
        pcat[(size_t)row * 192 + c] = f2bf(masks[(long long)row * 59 + (c - 118)]);
    else if (c >= 177)
        pcat[(size_t)row * 192 + c] = 0;
}

// ---------------------------------------------------------------------------
// Persistent recurrence: 127 GRU steps, both directions.
// 256 blocks x 512 thr, 1 block/CU. Weights LDS-resident, XOR-swizzled.
// h slab layout (shorts): slab t at t*262144; element (t, p, m, c) at
//   t*262144 + p*16384 + m*32 + c   (p = producer ublk = u>>5, c = u&31).
// Iteration t schedule (positions 0-2 = x chunks, 3-10 = h chunks) == R3:
//   top: issue h0,h1,h2 (sc0, spread start)
//   pos0: MFMA x0 | issue h3 | stage x1
//   pos1: MFMA x1 | issue h4 | stage x2 | issue rx=x(t+1) cached
//   pos2: MFMA x2 | vmcnt(7) stage h0 | issue h5
//   pos3: MFMA h0 | vmcnt(7) stage h1 | issue h6
//   pos4: MFMA h1 | vmcnt(7) stage h2 | issue h7
//   pos5..9: MFMA h2..h6 | vmcnt(7,6,2,1,0) stage h3..h7
//   pos10: MFMA h7
//   epilogue: GRU cell, dual h stores (sc0 + sc0sc1), vmcnt(0),
//   barrier (atomicAdd + agent-scope poll -- R3's proven mechanism)
// Issue ledger: h0,h1,h2,h3,h4,rx0,rx1,rx2,h5,h6,h7 (11 loads/iter).
// LDS: Bw 96x704 (135168 B) + As 2x64x64 (16384 B) = 151552 B.
// ---------------------------------------------------------------------------
__global__ __launch_bounds__(512)
void recurrence_kernel(const ushort_t* __restrict__ WhhB, const ushort_t* __restrict__ WihB,
                       const float* __restrict__ bih, const float* __restrict__ bhh,
                       const ushort_t* __restrict__ xcat_f, const ushort_t* __restrict__ xcat_b,
                       ushort_t* __restrict__ hfS, ushort_t* __restrict__ hbS,
                       unsigned* __restrict__ bar)
{
    extern __shared__ char smem_c[];
    ushort_t* Bw = (ushort_t*)smem_c;          // 96 x 704, col-chunk swizzled
    ushort_t* As = Bw + 96 * 704;              // 2 x 64 x 64, swizzled

    const int tid  = threadIdx.x;
    const int blk  = blockIdx.x;
    // remap: group members congruent mod 8 -> same XCD under round-robin
    const int ublk = blk >> 4;
    const int mblk = ((blk & 7) << 1) | ((blk >> 3) & 1);
    const int u0   = ublk * 32;
    const bool fwd = (mblk < 8);
    const int rbase = (fwd ? mblk : mblk - 8) * 64;
    const ushort_t* xbase = fwd ? xcat_f : xcat_b;
    ushort_t* hS = fwd ? hfS : hbS;
    unsigned* gctr = bar + (unsigned)mblk * 64;   // per-group counter, 256B apart

    // weight preload (cached loads): row g*32+u -> [Whh(512) | Wih(192)]
    for (int i = tid; i < 96 * 88; i += 512) {
        int row = i / 88, q = i - row * 88;
        int g = row >> 5, u = u0 + (row & 31);
        const ushort_t* src = (q < 64)
            ? WhhB + ((size_t)(g * 512 + u)) * 512 + q * 8
            : WihB + ((size_t)(g * 512 + u)) * 192 + (q - 64) * 8;
        int qs = q ^ (row & 7);
        *(u32x4*)&Bw[row * 704 + qs * 8] = *(const u32x4*)src;
    }

    const int lane = tid & 63, wv = tid >> 6;
    const int mt = wv >> 1, tc = wv & 1;
    const int l15 = lane & 15, lhi = lane >> 4;
    const int arow = tid >> 3, aj = tid & 7;
    const int awoff = arow * 64 + ((aj ^ (arow & 7)) * 8);
    const int aSw = l15 & 7;

    const int u = u0 + tc * 16 + l15;
    const int cl = tc * 16 + l15;              // c within producer stripe
    const float bR  = bih[u] + bhh[u];
    const float bZ  = bih[512 + u] + bhh[512 + u];
    const float bNX = bih[1024 + u];
    const float bNH = bhh[1024 + u];
    // pin bias materialization here, then drain all compiler-issued VMEM so
    // the manual vmcnt counts below are exact.
    asm volatile("" :: "v"(bR), "v"(bZ), "v"(bNX), "v"(bNH));
    asm volatile("s_waitcnt vmcnt(0) lgkmcnt(0)" ::: "memory");
    __syncthreads();   // weights staged

    f32x4 hreg = {0.f, 0.f, 0.f, 0.f};
    f32x4 zero = {0.f, 0.f, 0.f, 0.f};
    u32x4 rx[3];
    u32x4 rh[5];

    // MFMA for one 64-wide K position from As buffer `cbuf`, B col-chunk base jBbase
    auto mfma_pos = [&](int cbuf, int jBbase, f32x4& aR, f32x4& aZ, f32x4& accN) {
        const ushort_t* Ab = As + cbuf * 4096;
        #pragma unroll
        for (int ks = 0; ks < 64; ks += 32) {
            int j  = (ks >> 3) + lhi;
            int jB = jBbase + j;
            bf16x8 a  = *(const bf16x8*)&Ab[(mt * 16 + l15) * 64 + ((j ^ aSw) * 8)];
            bf16x8 b0 = *(const bf16x8*)&Bw[( 0 + tc * 16 + l15) * 704 + ((jB ^ aSw) * 8)];
            bf16x8 b1 = *(const bf16x8*)&Bw[(32 + tc * 16 + l15) * 704 + ((jB ^ aSw) * 8)];
            bf16x8 b2 = *(const bf16x8*)&Bw[(64 + tc * 16 + l15) * 704 + ((jB ^ aSw) * 8)];
            aR   = __builtin_amdgcn_mfma_f32_16x16x32_bf16(a, b0, aR, 0, 0, 0);
            aZ   = __builtin_amdgcn_mfma_f32_16x16x32_bf16(a, b1, aZ, 0, 0, 0);
            accN = __builtin_amdgcn_mfma_f32_16x16x32_bf16(a, b2, accN, 0, 0, 0);
        }
    };

    // consumer h offset: chunk j covers u = j*64 .. j*64+63
    //   p = 2j + (aj>>2), c = (aj&3)*8  ->  hoff + j*32768
    const size_t hoff = (size_t)(aj >> 2) * 16384
                      + (size_t)(rbase + arow) * 32 + (size_t)(aj & 3) * 8;

    // ---- prologue: x(0) cached loads, drained -----------------------------
    {
        const ushort_t* xr0 = xbase + (size_t)(rbase + arow) * 192 + aj * 8;
        rx[0] = load_b128_cached(xr0);
        rx[1] = load_b128_cached(xr0 + 64);
        rx[2] = load_b128_cached(xr0 + 128);
    }
    asm volatile("s_waitcnt vmcnt(0)" ::: "memory");

    for (int t = 0; t < 127; ++t) {
        const ushort_t* hslab = hS + (size_t)t * 262144 + hoff;
        ushort_t* hdst = hS + (size_t)(t + 1) * 262144;

        f32x4 accR = zero, accZ = zero, accNX = zero, accNH = zero;

        // top: issue h0..h2 (spread start of the depth-5 ring)
        rh[0] = load_b128_l2(hslab);
        rh[1] = load_b128_l2(hslab + 32768);
        rh[2] = load_b128_l2(hslab + 2 * 32768);

        // stage x0 -> buf0
        *(u32x4*)&As[awoff] = rx[0];
        __syncthreads();

        // pos 0: x0 (buf0)
        mfma_pos(0, 64, accR, accZ, accNX);
        rh[3] = load_b128_l2(hslab + 3 * 32768);
        *(u32x4*)&As[4096 + awoff] = rx[1];        // stage x1 -> buf1 (no wait)
        __syncthreads();

        // pos 1: x1 (buf1)
        mfma_pos(1, 72, accR, accZ, accNX);
        rh[4] = load_b128_l2(hslab + 4 * 32768);
        *(u32x4*)&As[awoff] = rx[2];               // stage x2 -> buf0 (no wait)
        {   // prefetch x(t+1) cached (drained pre-barrier)
            const ushort_t* xrn = xbase + (size_t)(t + 1) * 98304
                                + (size_t)(rbase + arow) * 192 + aj * 8;
            rx[0] = load_b128_cached(xrn);
            rx[1] = load_b128_cached(xrn + 64);
            rx[2] = load_b128_cached(xrn + 128);
        }
        __syncthreads();

        // pos 2: x2 (buf0)
        mfma_pos(0, 80, accR, accZ, accNX);
        asm volatile("s_waitcnt vmcnt(7)" ::: "memory");   // h0 done
        *(u32x4*)&As[4096 + awoff] = rh[0];                // stage h0 -> buf1
        rh[0] = load_b128_l2(hslab + 5 * 32768);           // issue h5
        __syncthreads();

        // pos 3: h0 (buf1)
        mfma_pos(1, 0, accR, accZ, accNH);
        asm volatile("s_waitcnt vmcnt(7)" ::: "memory");   // h1 done
        *(u32x4*)&As[awoff] = rh[1];                       // h1 -> buf0
        rh[1] = load_b128_l2(hslab + 6 * 32768);           // h6
        __syncthreads();

        // pos 4: h1 (buf0)
        mfma_pos(0, 8, accR, accZ, accNH);
        asm volatile("s_waitcnt vmcnt(7)" ::: "memory");   // h2 done
        *(u32x4*)&As[4096 + awoff] = rh[2];                // h2 -> buf1
        rh[2] = load_b128_l2(hslab + 7 * 32768);           // h7
        __syncthreads();

        // pos 5: h2 (buf1)
        mfma_pos(1, 16, accR, accZ, accNH);
        asm volatile("s_waitcnt vmcnt(7)" ::: "memory");   // h3 done
        *(u32x4*)&As[awoff] = rh[3];                       // h3 -> buf0
        __syncthreads();

        // pos 6: h3 (buf0)
        mfma_pos(0, 24, accR, accZ, accNH);
        asm volatile("s_waitcnt vmcnt(6)" ::: "memory");   // h4 done
        *(u32x4*)&As[4096 + awoff] = rh[4];                // h4 -> buf1
        __syncthreads();

        // pos 7: h4 (buf1)
        mfma_pos(1, 32, accR, accZ, accNH);
        asm volatile("s_waitcnt vmcnt(2)" ::: "memory");   // h5 done (rx drained too)
        *(u32x4*)&As[awoff] = rh[0];                       // h5 -> buf0
        __syncthreads();

        // pos 8: h5 (buf0)
        mfma_pos(0, 40, accR, accZ, accNH);
        asm volatile("s_waitcnt vmcnt(1)" ::: "memory");   // h6 done
        *(u32x4*)&As[4096 + awoff] = rh[1];                // h6 -> buf1
        __syncthreads();

        // pos 9: h6 (buf1)
        mfma_pos(1, 48, accR, accZ, accNH);
        asm volatile("s_waitcnt vmcnt(0)" ::: "memory");   // h7 done
        *(u32x4*)&As[awoff] = rh[2];                       // h7 -> buf0
        __syncthreads();

        // pos 10: h7 (buf0)
        mfma_pos(0, 56, accR, accZ, accNH);

        // ---- GRU cell epilogue; dual h stores (private-line layout) -------
        #pragma unroll
        for (int reg = 0; reg < 4; ++reg) {
            int m = rbase + mt * 16 + lhi * 4 + reg;
            float rr = fast_sigmoid(accR[reg] + bR);
            float zz = fast_sigmoid(accZ[reg] + bZ);
            float nn = fast_tanh(accNX[reg] + bNX + rr * (accNH[reg] + bNH));
            float hnew = (1.f - zz) * nn + zz * hreg[reg];
            hreg[reg] = hnew;
            unsigned hb16 = (unsigned)f2bf(hnew);
            ushort_t* dst = hdst + (size_t)ublk * 16384 + (size_t)m * 32 + cl;
            store_b16_l2(dst, hb16);     // local L2 (fast same-XCD reads)
            store_b16_mall(dst, hb16);   // MALL copy (cross-XCD correctness)
        }

        if (t < 126) {
            asm volatile("s_waitcnt vmcnt(0)" ::: "memory");  // stores drained
            __syncthreads();
            if (tid == 0) {
                atomicAdd(gctr, 1u);
                unsigned target = (unsigned)(t + 1) * 16u;
                while (__hip_atomic_load(gctr, __ATOMIC_RELAXED,
                                         __HIP_MEMORY_SCOPE_AGENT) < target)
                    __builtin_amdgcn_s_sleep(1);
            }
            __syncthreads();
        }
    }
}

// ---------------------------------------------------------------------------
// Fallback step kernel (used only if cooperative launch unavailable)
// ---------------------------------------------------------------------------
__global__ __launch_bounds__(512)
void step_kernel(const ushort_t* __restrict__ hsrcF, const ushort_t* __restrict__ hsrcB,
                 ushort_t* __restrict__ hdstF, ushort_t* __restrict__ hdstB,
                 const ushort_t* __restrict__ xF, const ushort_t* __restrict__ xB,
                 const ushort_t* __restrict__ WhhB, const ushort_t* __restrict__ WihB,
                 const float* __restrict__ bih, const float* __restrict__ bhh,
                 float* __restrict__ hstate)
{
    __shared__ __align__(16) ushort_t As[64 * 64];
    __shared__ __align__(16) ushort_t Bs[96 * 64];

    const int tid  = threadIdx.x;
    const int ublk = blockIdx.x;
    const int mblk = blockIdx.y;
    const int u0   = ublk * 32;
    const bool fwd = (mblk < 8);
    const ushort_t* hsrc = fwd ? hsrcF : hsrcB;
    const ushort_t* xsrc = fwd ? xF : xB;
    ushort_t* hdst = fwd ? hdstF : hdstB;
    const int rbase = (fwd ? mblk : mblk - 8) * 64;

    const int lane = tid & 63, wv = tid >> 6;
    const int mt = wv >> 1, tc = wv & 1;
    const int l15 = lane & 15, lhi = lane >> 4;

    f32x4 zero = {0.f, 0.f, 0.f, 0.f};
    f32x4 accR = zero, accZ = zero, accNH = zero, accNX = zero;
    const int arow = tid >> 3, ac8 = (tid & 7) * 8;

    for (int chunk = 0; chunk < 11; ++chunk) {
        const bool ph1 = (chunk < 8);
        {
            const ushort_t* src;
            if (ph1) {
                int p = 2 * chunk + (ac8 >> 5);
                src = hsrc + (size_t)p * 16384 + (size_t)(rbase + arow) * 32 + (ac8 & 31);
            } else {
                src = xsrc + ((size_t)(rbase + arow)) * 192 + (chunk - 8) * 64 + ac8;
            }
            *(uint4*)&As[arow * 64 + ac8] = *(const uint4*)src;
        }
        {
            int rowB = tid >> 3; int c8 = (tid & 7) * 8;
            int g = rowB >> 5; int u = u0 + (rowB & 31);
            const ushort_t* src = ph1
                ? WhhB + ((size_t)(g * 512 + u)) * 512 + chunk * 64 + c8
                : WihB + ((size_t)(g * 512 + u)) * 192 + (chunk - 8) * 64 + c8;
            *(uint4*)&Bs[rowB * 64 + c8] = *(const uint4*)src;
            if (tid < 256) {
                int u2 = tid + 512;
                rowB = u2 >> 3; c8 = (u2 & 7) * 8;
                g = rowB >> 5; u = u0 + (rowB & 31);
                src = ph1
                    ? WhhB + ((size_t)(g * 512 + u)) * 512 + chunk * 64 + c8
                    : WihB + ((size_t)(g * 512 + u)) * 192 + (chunk - 8) * 64 + c8;
                *(uint4*)&Bs[rowB * 64 + c8] = *(const uint4*)src;
            }
        }
        __syncthreads();
        #pragma unroll
        for (int ks = 0; ks < 64; ks += 32) {
            bf16x8 a  = *(const bf16x8*)&As[(mt * 16 + l15) * 64 + ks + lhi * 8];
            bf16x8 b0 = *(const bf16x8*)&Bs[( 0 + tc * 16 + l15) * 64 + ks + lhi * 8];
            bf16x8 b1 = *(const bf16x8*)&Bs[(32 + tc * 16 + l15) * 64 + ks + lhi * 8];
            bf16x8 b2 = *(const bf16x8*)&Bs[(64 + tc * 16 + l15) * 64 + ks + lhi * 8];
            accR = __builtin_amdgcn_mfma_f32_16x16x32_bf16(a, b0, accR, 0, 0, 0);
            accZ = __builtin_amdgcn_mfma_f32_16x16x32_bf16(a, b1, accZ, 0, 0, 0);
            if (ph1) accNH = __builtin_amdgcn_mfma_f32_16x16x32_bf16(a, b2, accNH, 0, 0, 0);
            else     accNX = __builtin_amdgcn_mfma_f32_16x16x32_bf16(a, b2, accNX, 0, 0, 0);
        }
        __syncthreads();
    }

    const int u = u0 + tc * 16 + l15;
    const float bR  = bih[u] + bhh[u];
    const float bZ  = bih[512 + u] + bhh[512 + u];
    const float bNX = bih[1024 + u];
    const float bNH = bhh[1024 + u];
    #pragma unroll
    for (int reg = 0; reg < 4; ++reg) {
        int m = mblk * 64 + mt * 16 + lhi * 4 + reg;
        float r = 1.f / (1.f + __expf(-(accR[reg] + bR)));
        float z = 1.f / (1.f + __expf(-(accZ[reg] + bZ)));
        float n = tanhf(accNX[reg] + bNX + r * (accNH[reg] + bNH));
        size_t idx = (size_t)m * 512 + u;
        float hold = hstate[idx];
        float hnew = (1.f - z) * n + z * hold;
        hstate[idx] = hnew;
        int ml = fwd ? m : m - 512;
        size_t bloc = (size_t)(u >> 5) * 16384 + (size_t)ml * 32 + (u & 31);
        hdst[bloc] = f2bf(hnew);
    }
}

// ---------------------------------------------------------------------------
// x_v = [hf, hb_rev] @ Wh^T + bh, written as bf16 into pcat cols 59..117
// h layout: element (t, m, u) at t*262144 + (u>>5)*16384 + m*32 + (u&31)
// ---------------------------------------------------------------------------
__global__ __launch_bounds__(256)
void xv_kernel(const ushort_t* __restrict__ hf, const ushort_t* __restrict__ hb,
               const ushort_t* __restrict__ WhpB, const float* __restrict__ bh,
               ushort_t* __restrict__ pcat)
{
    __shared__ __align__(16) ushort_t As[128 * 64];
    __shared__ __align__(16) ushort_t Bs[64 * 64];
    const int b = blockIdx.x;
    const int tid = threadIdx.x;
    const int lane = tid & 63, wv = tid >> 6;
    const int l15 = lane & 15, lhi = lane >> 4;

    f32x4 zero = {0.f, 0.f, 0.f, 0.f};
    f32x4 acc[2][4];
    #pragma unroll
    for (int i = 0; i < 2; ++i)
        #pragma unroll
        for (int j = 0; j < 4; ++j) acc[i][j] = zero;

    for (int chunk = 0; chunk < 16; ++chunk) {
        const bool fw = (chunk < 8);
        #pragma unroll
        for (int s = 0; s < 4; ++s) {
            int unit = tid + s * 256;
            int row = unit >> 3;             // time index 0..127
            int c8 = (unit & 7) * 8;
            int ch = fw ? chunk : (chunk - 8);
            int col = ch * 64 + c8;
            int p = col >> 5, cc = col & 31;
            int ti = fw ? row : (127 - row);
            const ushort_t* hbase = fw ? hf : hb;
            const ushort_t* src = hbase + (size_t)ti * 262144
                                + (size_t)p * 16384 + (size_t)b * 32 + cc;
            *(uint4*)&As[row * 64 + c8] = *(const uint4*)src;
        }
        #pragma unroll
        for (int s = 0; s < 2; ++s) {
            int unit = tid + s * 256;
            int row = unit >> 3;
            int c8 = (unit & 7) * 8;
            *(uint4*)&Bs[row * 64 + c8] =
                *(const uint4*)(WhpB + (size_t)row * 1024 + chunk * 64 + c8);
        }
        __syncthreads();
        #pragma unroll
        for (int ks = 0; ks < 64; ks += 32) {
            bf16x8 bfr[4];
            #pragma unroll
            for (int nt = 0; nt < 4; ++nt)
                bfr[nt] = *(const bf16x8*)&Bs[(nt * 16 + l15) * 64 + ks + lhi * 8];
            #pragma unroll
            for (int mt2 = 0; mt2 < 2; ++mt2) {
                bf16x8 a = *(const bf16x8*)&As[(wv * 32 + mt2 * 16 + l15) * 64 + ks + lhi * 8];
                #pragma unroll
                for (int nt = 0; nt < 4; ++nt)
                    acc[mt2][nt] = __builtin_amdgcn_mfma_f32_16x16x32_bf16(a, bfr[nt], acc[mt2][nt], 0, 0, 0);
            }
        }
        __syncthreads();
    }
    #pragma unroll
    for (int mt2 = 0; mt2 < 2; ++mt2) {
        #pragma unroll
        for (int nt = 0; nt < 4; ++nt) {
            int col = nt * 16 + l15;
            if (col < 59) {
                float bhc = bh[col];
                #pragma unroll
                for (int reg = 0; reg < 4; ++reg) {
                    int t = wv * 32 + mt2 * 16 + lhi * 4 + reg;
                    pcat[((size_t)b * 128 + t) * 192 + 59 + col] = f2bf(acc[mt2][nt][reg] + bhc);
                }
            }
        }
    }
}

// ---------------------------------------------------------------------------
// Fused post: two chained MFMA GEMMs + x_imp + loss partials
// ---------------------------------------------------------------------------
__global__ __launch_bounds__(256)
void post_kernel(const ushort_t* __restrict__ pcat,
                 const ushort_t* __restrict__ Wpost1, const ushort_t* __restrict__ Wpost2,
                 const float* __restrict__ bcP, const float* __restrict__ biP,
                 const float* __restrict__ values, const float* __restrict__ masks,
                 float* __restrict__ out, float* __restrict__ pnum, float* __restrict__ pden)
{
    __shared__ __align__(16) ushort_t A1[64 * 200];
    __shared__ __align__(16) ushort_t B1[64 * 200];
    __shared__ __align__(16) ushort_t B2[64 * 72];

    const int tid = threadIdx.x;
    const int blk = blockIdx.x;
    const int lane = tid & 63, wv = tid >> 6;
    const int l15 = lane & 15, lhi = lane >> 4;

    #pragma unroll
    for (int s = 0; s < 6; ++s) {
        int unit = tid + s * 256;
        int row = unit / 24, c8 = (unit % 24) * 8;
        *(uint4*)&A1[row * 200 + c8] =
            *(const uint4*)(pcat + ((size_t)blk * 64 + row) * 192 + c8);
        *(uint4*)&B1[row * 200 + c8] =
            *(const uint4*)(Wpost1 + (size_t)row * 192 + c8);
    }
    #pragma unroll
    for (int s = 0; s < 2; ++s) {
        int unit = tid + s * 256;
        int row = unit >> 3, c8 = (unit & 7) * 8;
        *(uint4*)&B2[row * 72 + c8] = *(const uint4*)(Wpost2 + (size_t)row * 64 + c8);
    }
    __syncthreads();

    f32x4 zero = {0.f, 0.f, 0.f, 0.f};
    f32x4 acc1[4];
    #pragma unroll
    for (int nt = 0; nt < 4; ++nt) acc1[nt] = zero;

    #pragma unroll
    for (int ks = 0; ks < 192; ks += 32) {
        bf16x8 a = *(const bf16x8*)&A1[(wv * 16 + l15) * 200 + ks + lhi * 8];
        #pragma unroll
        for (int nt = 0; nt < 4; ++nt) {
            bf16x8 bb = *(const bf16x8*)&B1[(nt * 16 + l15) * 200 + ks + lhi * 8];
            acc1[nt] = __builtin_amdgcn_mfma_f32_16x16x32_bf16(a, bb, acc1[nt], 0, 0, 0);
        }
    }
    __syncthreads();

    #pragma unroll
    for (int nt = 0; nt < 4; ++nt) {
        int col = nt * 16 + l15;
        float bcv = bcP[col];
        #pragma unroll
        for (int reg = 0; reg < 4; ++reg) {
            int row = wv * 16 + lhi * 4 + reg;
            A1[row * 72 + col] = f2bf(acc1[nt][reg] + bcv);
        }
    }
    __syncthreads();

    f32x4 acc2[4];
    #pragma unroll
    for (int nt = 0; nt < 4; ++nt) acc2[nt] = zero;
    #pragma unroll
    for (int ks = 0; ks < 64; ks += 32) {
        bf16x8 a = *(const bf16x8*)&A1[(wv * 16 + l15) * 72 + ks + lhi * 8];
        #pragma unroll
        for (int nt = 0; nt < 4; ++nt) {
            bf16x8 bb = *(const bf16x8*)&B2[(nt * 16 + l15) * 72 + ks + lhi * 8];
            acc2[nt] = __builtin_amdgcn_mfma_f32_16x16x32_bf16(a, bb, acc2[nt], 0, 0, 0);
        }
    }

    float biR[4];
    #pragma unroll
    for (int nt = 0; nt < 4; ++nt) biR[nt] = biP[nt * 16 + l15];

    #pragma unroll
    for (int reg = 0; reg < 4; ++reg) {
        size_t rowg = (size_t)blk * 64 + wv * 16 + lhi * 4 + reg;
        float esum = 0.f, dsum = 0.f;
        #pragma unroll
        for (int nt = 0; nt < 4; ++nt) {
            int col = nt * 16 + l15;
            if (col < 59) {
                float imp = acc2[nt][reg] + biR[nt];
                float v = values[rowg * 59 + col];
                float m = masks [rowg * 59 + col];
                out[rowg * 59 + col] = m * v + (1.f - m) * imp;
                esum += fabsf(v - imp) * m;
                dsum += m;
            }
        }
        #pragma unroll
        for (int o = 1; o < 16; o <<= 1) {
            esum += __shfl_xor(esum, o);
            dsum += __shfl_xor(dsum, o);
        }
        if (l15 == 0) { pnum[rowg] = esum; pden[rowg] = dsum; }
    }
}

// ---------------------------------------------------------------------------
// loss reduction (parallel): block t sums over b, atomicAdd num/(den+eps)
// ---------------------------------------------------------------------------
__global__ __launch_bounds__(256)
void loss_kernel(const float* __restrict__ pnum, const float* __restrict__ pden,
                 float* __restrict__ out)
{
    __shared__ float sn[4], sd[4];
    const int t = blockIdx.x;              // 0..127
    const int tid = threadIdx.x;
    float a = 0.f, b = 0.f;
    for (int bb = tid; bb < 512; bb += 256) {
        a += pnum[(size_t)bb * 128 + t];
        b += pden[(size_t)bb * 128 + t];
    }
    #pragma unroll
    for (int o = 32; o >= 1; o >>= 1) {
        a += __shfl_xor(a, o);
        b += __shfl_xor(b, o);
    }
    const int wv = tid >> 6;
    if ((tid & 63) == 0) { sn[wv] = a; sd[wv] = b; }
    __syncthreads();
    if (tid == 0) {
        float A = sn[0] + sn[1] + sn[2] + sn[3];
        float B = sd[0] + sd[1] + sd[2] + sd[3];
        atomicAdd(out + 3866624, A / (B + 1e-5f));   // B*T*V slot, zeroed by prep
    }
}

// ---------------------------------------------------------------------------
extern "C" void kernel_launch(void* const* d_in, const int* in_sizes, int n_in,
                              void* d_out, int out_size, void* d_ws, size_t ws_size,
                              hipStream_t stream)
{
    const float* values   = (const float*)d_in[0];
    const float* masks    = (const float*)d_in[1];
    const float* deltas_f = (const float*)d_in[2];
    const float* deltas_b = (const float*)d_in[3];
    const float* Wih = (const float*)d_in[4];
    const float* Whh = (const float*)d_in[5];
    const float* bih = (const float*)d_in[6];
    const float* bhh = (const float*)d_in[7];
    const float* Wh  = (const float*)d_in[8];
    const float* bh  = (const float*)d_in[9];
    const float* Wf  = (const float*)d_in[10];
    const float* bf_ = (const float*)d_in[11];
    const float* Wc  = (const float*)d_in[12];
    const float* bc  = (const float*)d_in[13];
    const float* Wi  = (const float*)d_in[14];
    const float* bi  = (const float*)d_in[15];
    float* out = (float*)d_out;

    uint8_t* ws = (uint8_t*)d_ws;
    size_t off = 0;
    auto alloc = [&](size_t bytes) -> void* {
        void* p = ws + off;
        off = (off + bytes + 255) & ~((size_t)255);
        return p;
    };
    ushort_t* xcat_f = (ushort_t*)alloc(128ULL * 512 * 192 * 2);
    ushort_t* xcat_b = (ushort_t*)alloc(128ULL * 512 * 192 * 2);
    ushort_t* WhhB   = (ushort_t*)alloc(1536ULL * 512 * 2);
    ushort_t* WihB   = (ushort_t*)alloc(1536ULL * 192 * 2);
    ushort_t* WhpB   = (ushort_t*)alloc(64ULL * 1024 * 2);
    ushort_t* hfS    = (ushort_t*)alloc(128ULL * 512 * 512 * 2);
    ushort_t* hbS    = (ushort_t*)alloc(128ULL * 512 * 512 * 2);
    float*    hstate = (float*)alloc(1024ULL * 512 * 4);
    ushort_t* pcat   = (ushort_t*)alloc(65536ULL * 192 * 2);
    ushort_t* Wpost1 = (ushort_t*)alloc(64ULL * 192 * 2);
    ushort_t* Wpost2 = (ushort_t*)alloc(64ULL * 64 * 2);
    float*    bcP    = (float*)alloc(64 * 4);
    float*    biP    = (float*)alloc(64 * 4);
    float*    pnum   = (float*)alloc(65536ULL * 4);
    float*    pden   = (float*)alloc(65536ULL * 4);
    unsigned* bar    = (unsigned*)alloc(16 * 64 * 4);

    prep_small<<<1024, 256, 0, stream>>>(Wih, Whh, Wh, Wf, bf_, Wc, bc, Wi, bi,
                                         WhhB, WihB, WhpB, hfS, hbS, hstate,
                                         Wpost1, Wpost2, bcP, biP, bar, out);
    prep_panels<<<65536, 192, 0, stream>>>(values, masks, deltas_f, deltas_b,
                                           xcat_f, xcat_b, pcat);

    // Persistent recurrence (per-group barriers); fallback: 127 step launches
    const unsigned smemBytes = (96u * 704u + 2u * 64u * 64u) * 2u;  // 151552 B
    hipError_t aerr = hipFuncSetAttribute((const void*)recurrence_kernel,
                                          hipFuncAttributeMaxDynamicSharedMemorySize,
                                          (int)smemBytes);
    hipError_t lerr = hipErrorUnknown;
    if (aerr == hipSuccess) {
        const ushort_t* a0 = WhhB; const ushort_t* a1 = WihB;
        const float* a2 = bih; const float* a3 = bhh;
        const ushort_t* a4 = xcat_f; const ushort_t* a5 = xcat_b;
        ushort_t* a6 = hfS; ushort_t* a7 = hbS;
        unsigned* a8 = bar;
        void* args[] = { &a0, &a1, &a2, &a3, &a4, &a5, &a6, &a7, &a8 };
        lerr = hipLaunchCooperativeKernel((const void*)recurrence_kernel,
                                          dim3(256), dim3(512), args, smemBytes, stream);
    }
    if (lerr != hipSuccess) {
        for (int t = 0; t < 127; ++t) {
            step_kernel<<<dim3(16, 16), 512, 0, stream>>>(
                hfS + (size_t)t * 512 * 512, hbS + (size_t)t * 512 * 512,
                hfS + (size_t)(t + 1) * 512 * 512, hbS + (size_t)(t + 1) * 512 * 512,
                xcat_f + (size_t)t * 512 * 192, xcat_b + (size_t)t * 512 * 192,
                WhhB, WihB, bih, bhh, hstate);
        }
    }

    xv_kernel<<<512, 256, 0, stream>>>(hfS, hbS, WhpB, bh, pcat);
    post_kernel<<<1024, 256, 0, stream>>>(pcat, Wpost1, Wpost2, bcP, biP,
                                          values, masks, out, pnum, pden);
    loss_kernel<<<128, 256, 0, stream>>>(pnum, pden, out);
}

// Round 7
// 796.622 us; speedup vs baseline: 3.9067x; 3.6842x over previous
//
#include <hip/hip_runtime.h>
#include <stdint.h>

// M-RNN bidirectional GRU imputation for MI355X (gfx950).
// B=512, T=128, V=59, H=512. bf16 MFMA + fp32 state in registers.
// R7 = the proven 600us R3 kernel (depth-5 spread h ring, LDS A-staging,
// [t][m][u] h layout, single sc0sc1 h stores) with exactly two changes:
//   (a) h loads are `sc0` (L2+MALL allowed) instead of `sc0 sc1`:
//       stores are ACKed at MALL/HBM before the barrier, and slab addresses
//       are t-unique (never previously cached by any consumer L2), so no
//       stale-line hazard exists. If sc0sc1 stores allocate in MALL, loads
//       now fill from MALL (~600cyc) instead of HBM (~900cyc) -- R3's
//       FETCH=719MB says its sc0sc1 loads were going all the way to HBM.
//   (b) group barrier = single-writer slot stores (128B-spaced, sc0sc1) +
//       16-lane ballot poll with vmcnt(0) probes, replacing 16 serialized
//       atomicAdds on one MALL address. (R4's mechanism, poll bug fixed.)
// NO dual stores anywhere (R4/R6 showed same-address sc0+sc0sc1 pairs
// serialize catastrophically in the memory pipeline).

typedef unsigned short ushort_t;
typedef __bf16 bf16x8 __attribute__((ext_vector_type(8)));
typedef float f32x4 __attribute__((ext_vector_type(4)));
typedef unsigned int u32x4 __attribute__((ext_vector_type(4)));

__device__ __forceinline__ ushort_t f2bf(float f) {
    union { float f; uint32_t u; } c; c.f = f;
    uint32_t u = c.u;
    uint32_t r = (u + 0x7FFFu + ((u >> 16) & 1u)) >> 16;
    return (ushort_t)r;
}

// ---- memory helpers (asm so manual vmcnt counting stays exact) -----------
__device__ __forceinline__ u32x4 load_b128_cached(const void* p) {
    u32x4 d;
    asm volatile("global_load_dwordx4 %0, %1, off" : "=v"(d) : "v"(p) : "memory");
    return d;
}
__device__ __forceinline__ u32x4 load_b128_l2(const void* p) {   // bypass L1 only
    u32x4 d;
    asm volatile("global_load_dwordx4 %0, %1, off sc0" : "=v"(d) : "v"(p) : "memory");
    return d;
}
__device__ __forceinline__ void store_b16_mall(void* p, unsigned v) {
    asm volatile("global_store_short %0, %1, off sc0 sc1" :: "v"(p), "v"(v) : "memory");
}
__device__ __forceinline__ void store_u32_mall(void* p, unsigned v) {
    asm volatile("global_store_dword %0, %1, off sc0 sc1" :: "v"(p), "v"(v) : "memory");
}

__device__ __forceinline__ float fast_sigmoid(float x) {
    float e = __expf(-x);
    return __builtin_amdgcn_rcpf(1.f + e);
}
__device__ __forceinline__ float fast_tanh(float x) {
    float xc = fminf(fmaxf(x, -15.f), 15.f);
    float e = __expf(-2.f * xc);
    return (1.f - e) * __builtin_amdgcn_rcpf(1.f + e);
}

// ---------------------------------------------------------------------------
// prep_small: barrier slots, slot-0 zeros, bf16 weights, post weights
// ---------------------------------------------------------------------------
__global__ void prep_small(const float* __restrict__ Wih, const float* __restrict__ Whh,
                           const float* __restrict__ Wh,
                           const float* __restrict__ Wf, const float* __restrict__ bf_,
                           const float* __restrict__ Wc, const float* __restrict__ bc,
                           const float* __restrict__ Wi, const float* __restrict__ bi,
                           ushort_t* __restrict__ WhhB, ushort_t* __restrict__ WihB,
                           ushort_t* __restrict__ WhpB,
                           ushort_t* __restrict__ hf0, ushort_t* __restrict__ hb0,
                           float* __restrict__ hstate,
                           ushort_t* __restrict__ Wpost1, ushort_t* __restrict__ Wpost2,
                           float* __restrict__ bcP, float* __restrict__ biP,
                           unsigned* __restrict__ bar, float* __restrict__ outp)
{
    long long gid = (long long)blockIdx.x * blockDim.x + threadIdx.x;
    long long stride = (long long)gridDim.x * blockDim.x;

    if (gid == 0) outp[3866624] = 0.f;   // loss accumulator slot
    for (long long i = gid; i < 16LL * 16 * 32; i += stride) bar[i] = 0u;
    for (long long i = gid; i < 1024LL * 512; i += stride) hstate[i] = 0.f;
    for (long long i = gid; i < 512LL * 512; i += stride) { hf0[i] = 0; hb0[i] = 0; }
    for (long long i = gid; i < 1536LL * 512; i += stride) WhhB[i] = f2bf(Whh[i]);
    for (long long i = gid; i < 1536LL * 192; i += stride) {
        int n = (int)(i / 192), c = (int)(i % 192);
        WihB[i] = (c < 177) ? f2bf(Wih[n * 177 + c]) : (ushort_t)0;
    }
    for (long long i = gid; i < 64LL * 1024; i += stride) {
        int n = (int)(i >> 10), k = (int)(i & 1023);
        WhpB[i] = (n < 59) ? f2bf(Wh[n * 1024 + k]) : (ushort_t)0;
    }
    for (long long i = gid; i < 64LL * 192; i += stride) {
        int n = (int)(i / 192), c = (int)(i % 192);
        float w = 0.f;
        if (n < 59) {
            if (c < 59)       w = (c == n) ? 0.f : Wf[n * 59 + c];
            else if (c < 118) w = Wc[n * 118 + (c - 59)];
            else if (c < 177) w = Wc[n * 118 + 59 + (c - 118)];
        }
        Wpost1[i] = f2bf(w);
    }
    for (long long i = gid; i < 64LL * 64; i += stride) {
        int n = (int)(i >> 6), k = (int)(i & 63);
        Wpost2[i] = (n < 59 && k < 59) ? f2bf(Wi[n * 59 + k]) : (ushort_t)0;
    }
    for (long long i = gid; i < 64; i += stride) {
        bcP[i] = (i < 59) ? (bf_[i] + bc[i]) : 0.f;
        biP[i] = (i < 59) ? bi[i] : 0.f;
    }
}

// ---------------------------------------------------------------------------
// prep_panels: xcat_f / xcat_b / pcat, div-free (block = one (b,t) row)
// ---------------------------------------------------------------------------
__global__ __launch_bounds__(192)
void prep_panels(const float* __restrict__ values, const float* __restrict__ masks,
                 const float* __restrict__ deltas_f, const float* __restrict__ deltas_b,
                 ushort_t* __restrict__ xcat_f, ushort_t* __restrict__ xcat_b,
                 ushort_t* __restrict__ pcat)
{
    const int row = blockIdx.x;            // b*128 + t
    const int c = threadIdx.x;             // 0..191
    const int b = row >> 7, t = row & 127;
    const int tr = 127 - t;
    const long long rowr = (long long)b * 128 + tr;

    float vf = 0.f;
    if (c < 59)       vf = values  [(long long)row * 59 + c];
    else if (c < 118) vf = masks   [(long long)row * 59 + (c - 59)];
    else if (c < 177) vf = deltas_f[(long long)row * 59 + (c - 118)];
    xcat_f[((size_t)t * 512 + b) * 192 + c] = (c < 177) ? f2bf(vf) : (ushort_t)0;

    float vb = 0.f;
    if (c < 59)       vb = values  [rowr * 59 + c];
    else if (c < 118) vb = masks   [rowr * 59 + (c - 59)];
    else if (c < 177) vb = deltas_b[(long long)row * 59 + (c - 118)];
    xcat_b[((size_t)t * 512 + b) * 192 + c] = (c < 177) ? f2bf(vb) : (ushort_t)0;

    if (c < 59)
        pcat[(size_t)row * 192 + c] = f2bf(values[(long long)row * 59 + c]);
    else if (c >= 118 && c < 177)
        pcat[(size_t)row * 192 + c] = f2bf(masks[(long long)row * 59 + (c - 118)]);
    else if (c >= 177)
        pcat[(size_t)row * 192 + c] = 0;
}

// ---------------------------------------------------------------------------
// Persistent recurrence: 127 GRU steps, both directions.
// 256 blocks x 512 thr, 1 block/CU. Weights LDS-resident, XOR-swizzled.
// Iteration t schedule (positions 0-2 = x chunks, 3-10 = h chunks):
//   top: issue h0,h1,h2 (sc0, spread start of depth-5 ring)
//   pos0: MFMA x0 | issue h3 | stage x1
//   pos1: MFMA x1 | issue h4 | stage x2 | issue rx=x(t+1) cached
//   pos2: MFMA x2 | vmcnt(7) stage h0 | issue h5
//   pos3: MFMA h0 | vmcnt(7) stage h1 | issue h6
//   pos4: MFMA h1 | vmcnt(7) stage h2 | issue h7
//   pos5..9: MFMA h2..h6 | vmcnt(7,6,2,1,0) stage h3..h7
//   pos10: MFMA h7
//   epilogue: GRU cell, h stores sc0sc1, vmcnt(0), slot+ballot barrier
// Issue ledger: h0,h1,h2,h3,h4,rx0,rx1,rx2,h5,h6,h7 (11 loads/iter).
// Barrier: slot(mblk,ublk) at bar[(mblk*16+ublk)*32] (128B-spaced); writer =
// tid0 sc0sc1 store of t+1 AFTER data drain; wv0 lanes 0-15 probe the 16
// slots (skip own) with vmcnt(0) before every ballot.
// LDS: Bw 96x704 (135168 B) + As 2x64x64 (16384 B) = 151552 B.
// ---------------------------------------------------------------------------
__global__ __launch_bounds__(512)
void recurrence_kernel(const ushort_t* __restrict__ WhhB, const ushort_t* __restrict__ WihB,
                       const float* __restrict__ bih, const float* __restrict__ bhh,
                       const ushort_t* __restrict__ xcat_f, const ushort_t* __restrict__ xcat_b,
                       ushort_t* __restrict__ hfS, ushort_t* __restrict__ hbS,
                       unsigned* __restrict__ bar)
{
    extern __shared__ char smem_c[];
    ushort_t* Bw = (ushort_t*)smem_c;          // 96 x 704, col-chunk swizzled
    ushort_t* As = Bw + 96 * 704;              // 2 x 64 x 64, swizzled

    const int tid  = threadIdx.x;
    const int blk  = blockIdx.x;
    const int ublk = blk & 15;
    const int mblk = blk >> 4;
    const int u0   = ublk * 32;
    const bool fwd = (mblk < 8);
    const int rbase = (fwd ? mblk : mblk - 8) * 64;
    const ushort_t* xbase = fwd ? xcat_f : xcat_b;
    ushort_t* hS = fwd ? hfS : hbS;

    // weight preload (cached loads): row g*32+u -> [Whh(512) | Wih(192)]
    for (int i = tid; i < 96 * 88; i += 512) {
        int row = i / 88, q = i - row * 88;
        int g = row >> 5, u = u0 + (row & 31);
        const ushort_t* src = (q < 64)
            ? WhhB + ((size_t)(g * 512 + u)) * 512 + q * 8
            : WihB + ((size_t)(g * 512 + u)) * 192 + (q - 64) * 8;
        int qs = q ^ (row & 7);
        *(u32x4*)&Bw[row * 704 + qs * 8] = *(const u32x4*)src;
    }

    const int lane = tid & 63, wv = tid >> 6;
    const int mt = wv >> 1, tc = wv & 1;
    const int l15 = lane & 15, lhi = lane >> 4;
    const int arow = tid >> 3, aj = tid & 7;
    const int awoff = arow * 64 + ((aj ^ (arow & 7)) * 8);
    const int aSw = l15 & 7;

    // barrier slots (128B-spaced uints)
    unsigned* myslot = bar + ((size_t)(mblk * 16 + ublk)) * 32;
    const unsigned* pollp = bar + ((size_t)(mblk * 16 + (lane & 15))) * 32;

    const int u = u0 + tc * 16 + l15;
    const float bR  = bih[u] + bhh[u];
    const float bZ  = bih[512 + u] + bhh[512 + u];
    const float bNX = bih[1024 + u];
    const float bNH = bhh[1024 + u];
    // pin bias materialization here, then drain all compiler-issued VMEM so
    // the manual vmcnt counts below are exact.
    asm volatile("" :: "v"(bR), "v"(bZ), "v"(bNX), "v"(bNH));
    asm volatile("s_waitcnt vmcnt(0) lgkmcnt(0)" ::: "memory");
    __syncthreads();   // weights staged

    f32x4 hreg = {0.f, 0.f, 0.f, 0.f};
    f32x4 zero = {0.f, 0.f, 0.f, 0.f};
    u32x4 rx[3];
    u32x4 rh[5];

    // MFMA for one 64-wide K position from As buffer `cbuf`, B col-chunk base jBbase
    auto mfma_pos = [&](int cbuf, int jBbase, f32x4& aR, f32x4& aZ, f32x4& accN) {
        const ushort_t* Ab = As + cbuf * 4096;
        #pragma unroll
        for (int ks = 0; ks < 64; ks += 32) {
            int j  = (ks >> 3) + lhi;
            int jB = jBbase + j;
            bf16x8 a  = *(const bf16x8*)&Ab[(mt * 16 + l15) * 64 + ((j ^ aSw) * 8)];
            bf16x8 b0 = *(const bf16x8*)&Bw[( 0 + tc * 16 + l15) * 704 + ((jB ^ aSw) * 8)];
            bf16x8 b1 = *(const bf16x8*)&Bw[(32 + tc * 16 + l15) * 704 + ((jB ^ aSw) * 8)];
            bf16x8 b2 = *(const bf16x8*)&Bw[(64 + tc * 16 + l15) * 704 + ((jB ^ aSw) * 8)];
            aR   = __builtin_amdgcn_mfma_f32_16x16x32_bf16(a, b0, aR, 0, 0, 0);
            aZ   = __builtin_amdgcn_mfma_f32_16x16x32_bf16(a, b1, aZ, 0, 0, 0);
            accN = __builtin_amdgcn_mfma_f32_16x16x32_bf16(a, b2, accN, 0, 0, 0);
        }
    };

    // ---- prologue: x(0) cached loads, drained -----------------------------
    {
        const ushort_t* xr0 = xbase + (size_t)(rbase + arow) * 192 + aj * 8;
        rx[0] = load_b128_cached(xr0);
        rx[1] = load_b128_cached(xr0 + 64);
        rx[2] = load_b128_cached(xr0 + 128);
    }
    asm volatile("s_waitcnt vmcnt(0)" ::: "memory");

    for (int t = 0; t < 127; ++t) {
        const ushort_t* hrow = hS + (size_t)t * 262144 + (size_t)(rbase + arow) * 512 + aj * 8;
        ushort_t* hdst = hS + (size_t)(t + 1) * 262144;

        f32x4 accR = zero, accZ = zero, accNX = zero, accNH = zero;

        // top: issue h0..h2 (spread start of the depth-5 ring; sc0 loads)
        rh[0] = load_b128_l2(hrow);
        rh[1] = load_b128_l2(hrow + 64);
        rh[2] = load_b128_l2(hrow + 128);

        // stage x0 -> buf0
        *(u32x4*)&As[awoff] = rx[0];
        __syncthreads();

        // pos 0: x0 (buf0)
        mfma_pos(0, 64, accR, accZ, accNX);
        rh[3] = load_b128_l2(hrow + 3 * 64);
        *(u32x4*)&As[4096 + awoff] = rx[1];        // stage x1 -> buf1 (no wait)
        __syncthreads();

        // pos 1: x1 (buf1)
        mfma_pos(1, 72, accR, accZ, accNX);
        rh[4] = load_b128_l2(hrow + 4 * 64);
        *(u32x4*)&As[awoff] = rx[2];               // stage x2 -> buf0 (no wait)
        {   // prefetch x(t+1) cached (drained pre-barrier)
            const ushort_t* xrn = xbase + (size_t)(t + 1) * 98304
                                + (size_t)(rbase + arow) * 192 + aj * 8;
            rx[0] = load_b128_cached(xrn);
            rx[1] = load_b128_cached(xrn + 64);
            rx[2] = load_b128_cached(xrn + 128);
        }
        __syncthreads();

        // pos 2: x2 (buf0)
        mfma_pos(0, 80, accR, accZ, accNX);
        asm volatile("s_waitcnt vmcnt(7)" ::: "memory");   // h0 done
        *(u32x4*)&As[4096 + awoff] = rh[0];                // stage h0 -> buf1
        rh[0] = load_b128_l2(hrow + 5 * 64);               // issue h5
        __syncthreads();

        // pos 3: h0 (buf1)
        mfma_pos(1, 0, accR, accZ, accNH);
        asm volatile("s_waitcnt vmcnt(7)" ::: "memory");   // h1 done
        *(u32x4*)&As[awoff] = rh[1];                       // h1 -> buf0
        rh[1] = load_b128_l2(hrow + 6 * 64);               // h6
        __syncthreads();

        // pos 4: h1 (buf0)
        mfma_pos(0, 8, accR, accZ, accNH);
        asm volatile("s_waitcnt vmcnt(7)" ::: "memory");   // h2 done
        *(u32x4*)&As[4096 + awoff] = rh[2];                // h2 -> buf1
        rh[2] = load_b128_l2(hrow + 7 * 64);               // h7
        __syncthreads();

        // pos 5: h2 (buf1)
        mfma_pos(1, 16, accR, accZ, accNH);
        asm volatile("s_waitcnt vmcnt(7)" ::: "memory");   // h3 done
        *(u32x4*)&As[awoff] = rh[3];                       // h3 -> buf0
        __syncthreads();

        // pos 6: h3 (buf0)
        mfma_pos(0, 24, accR, accZ, accNH);
        asm volatile("s_waitcnt vmcnt(6)" ::: "memory");   // h4 done
        *(u32x4*)&As[4096 + awoff] = rh[4];                // h4 -> buf1
        __syncthreads();

        // pos 7: h4 (buf1)
        mfma_pos(1, 32, accR, accZ, accNH);
        asm volatile("s_waitcnt vmcnt(2)" ::: "memory");   // h5 done (rx drained too)
        *(u32x4*)&As[awoff] = rh[0];                       // h5 -> buf0
        __syncthreads();

        // pos 8: h5 (buf0)
        mfma_pos(0, 40, accR, accZ, accNH);
        asm volatile("s_waitcnt vmcnt(1)" ::: "memory");   // h6 done
        *(u32x4*)&As[4096 + awoff] = rh[1];                // h6 -> buf1
        __syncthreads();

        // pos 9: h6 (buf1)
        mfma_pos(1, 48, accR, accZ, accNH);
        asm volatile("s_waitcnt vmcnt(0)" ::: "memory");   // h7 done
        *(u32x4*)&As[awoff] = rh[2];                       // h7 -> buf0
        __syncthreads();

        // pos 10: h7 (buf0)
        mfma_pos(0, 56, accR, accZ, accNH);

        // ---- GRU cell epilogue; h out via single sc0sc1 stores ------------
        #pragma unroll
        for (int reg = 0; reg < 4; ++reg) {
            int m = rbase + mt * 16 + lhi * 4 + reg;
            float rr = fast_sigmoid(accR[reg] + bR);
            float zz = fast_sigmoid(accZ[reg] + bZ);
            float nn = fast_tanh(accNX[reg] + bNX + rr * (accNH[reg] + bNH));
            float hnew = (1.f - zz) * nn + zz * hreg[reg];
            hreg[reg] = hnew;
            store_b16_mall(hdst + (size_t)m * 512 + u, (unsigned)f2bf(hnew));
        }

        if (t < 126) {
            asm volatile("s_waitcnt vmcnt(0)" ::: "memory");  // data stores ACKed
            __syncthreads();
            // writer: publish arrival AFTER the data drain
            if (tid == 0) store_u32_mall(myslot, (unsigned)(t + 1));
            // 16-lane parallel ballot poll (wave 0 only), vmcnt(0) per probe
            if (wv == 0) {
                const unsigned target = (unsigned)(t + 1);
                const bool need = (lane < 16) && (lane != ublk);
                for (;;) {
                    unsigned v = 0;
                    if (need) {
                        asm volatile("global_load_dword %0, %1, off sc0 sc1"
                                     : "=v"(v) : "v"(pollp) : "memory");
                    }
                    asm volatile("s_waitcnt vmcnt(0)" ::: "memory");
                    bool ok = need ? (v >= target) : true;
                    if (__ballot(ok) == ~0ULL) break;
                    __builtin_amdgcn_s_sleep(1);
                }
            }
            __syncthreads();
        }
    }
}

// ---------------------------------------------------------------------------
// Fallback step kernel (used only if cooperative launch unavailable)
// ---------------------------------------------------------------------------
__global__ __launch_bounds__(512)
void step_kernel(const ushort_t* __restrict__ hsrcF, const ushort_t* __restrict__ hsrcB,
                 ushort_t* __restrict__ hdstF, ushort_t* __restrict__ hdstB,
                 const ushort_t* __restrict__ xF, const ushort_t* __restrict__ xB,
                 const ushort_t* __restrict__ WhhB, const ushort_t* __restrict__ WihB,
                 const float* __restrict__ bih, const float* __restrict__ bhh,
                 float* __restrict__ hstate)
{
    __shared__ __align__(16) ushort_t As[64 * 64];
    __shared__ __align__(16) ushort_t Bs[96 * 64];

    const int tid  = threadIdx.x;
    const int ublk = blockIdx.x;
    const int mblk = blockIdx.y;
    const int u0   = ublk * 32;
    const bool fwd = (mblk < 8);
    const ushort_t* hsrc = fwd ? hsrcF : hsrcB;
    const ushort_t* xsrc = fwd ? xF : xB;
    ushort_t* hdst = fwd ? hdstF : hdstB;
    const int rbase = (fwd ? mblk : mblk - 8) * 64;

    const int lane = tid & 63, wv = tid >> 6;
    const int mt = wv >> 1, tc = wv & 1;
    const int l15 = lane & 15, lhi = lane >> 4;

    f32x4 zero = {0.f, 0.f, 0.f, 0.f};
    f32x4 accR = zero, accZ = zero, accNH = zero, accNX = zero;
    const int arow = tid >> 3, ac8 = (tid & 7) * 8;

    for (int chunk = 0; chunk < 11; ++chunk) {
        const bool ph1 = (chunk < 8);
        {
            const ushort_t* src = ph1
                ? hsrc + ((size_t)(rbase + arow)) * 512 + chunk * 64 + ac8
                : xsrc + ((size_t)(rbase + arow)) * 192 + (chunk - 8) * 64 + ac8;
            *(uint4*)&As[arow * 64 + ac8] = *(const uint4*)src;
        }
        {
            int rowB = tid >> 3; int c8 = (tid & 7) * 8;
            int g = rowB >> 5; int u = u0 + (rowB & 31);
            const ushort_t* src = ph1
                ? WhhB + ((size_t)(g * 512 + u)) * 512 + chunk * 64 + c8
                : WihB + ((size_t)(g * 512 + u)) * 192 + (chunk - 8) * 64 + c8;
            *(uint4*)&Bs[rowB * 64 + c8] = *(const uint4*)src;
            if (tid < 256) {
                int u2 = tid + 512;
                rowB = u2 >> 3; c8 = (u2 & 7) * 8;
                g = rowB >> 5; u = u0 + (rowB & 31);
                src = ph1
                    ? WhhB + ((size_t)(g * 512 + u)) * 512 + chunk * 64 + c8
                    : WihB + ((size_t)(g * 512 + u)) * 192 + (chunk - 8) * 64 + c8;
                *(uint4*)&Bs[rowB * 64 + c8] = *(const uint4*)src;
            }
        }
        __syncthreads();
        #pragma unroll
        for (int ks = 0; ks < 64; ks += 32) {
            bf16x8 a  = *(const bf16x8*)&As[(mt * 16 + l15) * 64 + ks + lhi * 8];
            bf16x8 b0 = *(const bf16x8*)&Bs[( 0 + tc * 16 + l15) * 64 + ks + lhi * 8];
            bf16x8 b1 = *(const bf16x8*)&Bs[(32 + tc * 16 + l15) * 64 + ks + lhi * 8];
            bf16x8 b2 = *(const bf16x8*)&Bs[(64 + tc * 16 + l15) * 64 + ks + lhi * 8];
            accR = __builtin_amdgcn_mfma_f32_16x16x32_bf16(a, b0, accR, 0, 0, 0);
            accZ = __builtin_amdgcn_mfma_f32_16x16x32_bf16(a, b1, accZ, 0, 0, 0);
            if (ph1) accNH = __builtin_amdgcn_mfma_f32_16x16x32_bf16(a, b2, accNH, 0, 0, 0);
            else     accNX = __builtin_amdgcn_mfma_f32_16x16x32_bf16(a, b2, accNX, 0, 0, 0);
        }
        __syncthreads();
    }

    const int u = u0 + tc * 16 + l15;
    const float bR  = bih[u] + bhh[u];
    const float bZ  = bih[512 + u] + bhh[512 + u];
    const float bNX = bih[1024 + u];
    const float bNH = bhh[1024 + u];
    #pragma unroll
    for (int reg = 0; reg < 4; ++reg) {
        int m = mblk * 64 + mt * 16 + lhi * 4 + reg;
        float r = 1.f / (1.f + __expf(-(accR[reg] + bR)));
        float z = 1.f / (1.f + __expf(-(accZ[reg] + bZ)));
        float n = tanhf(accNX[reg] + bNX + r * (accNH[reg] + bNH));
        size_t idx = (size_t)m * 512 + u;
        float hold = hstate[idx];
        float hnew = (1.f - z) * n + z * hold;
        hstate[idx] = hnew;
        size_t bloc = (size_t)(fwd ? m : m - 512) * 512 + u;
        hdst[bloc] = f2bf(hnew);
    }
}

// ---------------------------------------------------------------------------
// x_v = [hf, hb_rev] @ Wh^T + bh, written as bf16 into pcat cols 59..117
// ---------------------------------------------------------------------------
__global__ __launch_bounds__(256)
void xv_kernel(const ushort_t* __restrict__ hf, const ushort_t* __restrict__ hb,
               const ushort_t* __restrict__ WhpB, const float* __restrict__ bh,
               ushort_t* __restrict__ pcat)
{
    __shared__ __align__(16) ushort_t As[128 * 64];
    __shared__ __align__(16) ushort_t Bs[64 * 64];
    const int b = blockIdx.x;
    const int tid = threadIdx.x;
    const int lane = tid & 63, wv = tid >> 6;
    const int l15 = lane & 15, lhi = lane >> 4;

    f32x4 zero = {0.f, 0.f, 0.f, 0.f};
    f32x4 acc[2][4];
    #pragma unroll
    for (int i = 0; i < 2; ++i)
        #pragma unroll
        for (int j = 0; j < 4; ++j) acc[i][j] = zero;

    for (int chunk = 0; chunk < 16; ++chunk) {
        const bool fw = (chunk < 8);
        #pragma unroll
        for (int s = 0; s < 4; ++s) {
            int unit = tid + s * 256;
            int row = unit >> 3;
            int c8 = (unit & 7) * 8;
            const ushort_t* src = fw
                ? hf + ((size_t)row * 512 + b) * 512 + chunk * 64 + c8
                : hb + ((size_t)(127 - row) * 512 + b) * 512 + (chunk - 8) * 64 + c8;
            *(uint4*)&As[row * 64 + c8] = *(const uint4*)src;
        }
        #pragma unroll
        for (int s = 0; s < 2; ++s) {
            int unit = tid + s * 256;
            int row = unit >> 3;
            int c8 = (unit & 7) * 8;
            *(uint4*)&Bs[row * 64 + c8] =
                *(const uint4*)(WhpB + (size_t)row * 1024 + chunk * 64 + c8);
        }
        __syncthreads();
        #pragma unroll
        for (int ks = 0; ks < 64; ks += 32) {
            bf16x8 bfr[4];
            #pragma unroll
            for (int nt = 0; nt < 4; ++nt)
                bfr[nt] = *(const bf16x8*)&Bs[(nt * 16 + l15) * 64 + ks + lhi * 8];
            #pragma unroll
            for (int mt2 = 0; mt2 < 2; ++mt2) {
                bf16x8 a = *(const bf16x8*)&As[(wv * 32 + mt2 * 16 + l15) * 64 + ks + lhi * 8];
                #pragma unroll
                for (int nt = 0; nt < 4; ++nt)
                    acc[mt2][nt] = __builtin_amdgcn_mfma_f32_16x16x32_bf16(a, bfr[nt], acc[mt2][nt], 0, 0, 0);
            }
        }
        __syncthreads();
    }
    #pragma unroll
    for (int mt2 = 0; mt2 < 2; ++mt2) {
        #pragma unroll
        for (int nt = 0; nt < 4; ++nt) {
            int col = nt * 16 + l15;
            if (col < 59) {
                float bhc = bh[col];
                #pragma unroll
                for (int reg = 0; reg < 4; ++reg) {
                    int t = wv * 32 + mt2 * 16 + lhi * 4 + reg;
                    pcat[((size_t)b * 128 + t) * 192 + 59 + col] = f2bf(acc[mt2][nt][reg] + bhc);
                }
            }
        }
    }
}

// ---------------------------------------------------------------------------
// Fused post: two chained MFMA GEMMs + x_imp + loss partials
// ---------------------------------------------------------------------------
__global__ __launch_bounds__(256)
void post_kernel(const ushort_t* __restrict__ pcat,
                 const ushort_t* __restrict__ Wpost1, const ushort_t* __restrict__ Wpost2,
                 const float* __restrict__ bcP, const float* __restrict__ biP,
                 const float* __restrict__ values, const float* __restrict__ masks,
                 float* __restrict__ out, float* __restrict__ pnum, float* __restrict__ pden)
{
    __shared__ __align__(16) ushort_t A1[64 * 200];
    __shared__ __align__(16) ushort_t B1[64 * 200];
    __shared__ __align__(16) ushort_t B2[64 * 72];

    const int tid = threadIdx.x;
    const int blk = blockIdx.x;
    const int lane = tid & 63, wv = tid >> 6;
    const int l15 = lane & 15, lhi = lane >> 4;

    #pragma unroll
    for (int s = 0; s < 6; ++s) {
        int unit = tid + s * 256;
        int row = unit / 24, c8 = (unit % 24) * 8;
        *(uint4*)&A1[row * 200 + c8] =
            *(const uint4*)(pcat + ((size_t)blk * 64 + row) * 192 + c8);
        *(uint4*)&B1[row * 200 + c8] =
            *(const uint4*)(Wpost1 + (size_t)row * 192 + c8);
    }
    #pragma unroll
    for (int s = 0; s < 2; ++s) {
        int unit = tid + s * 256;
        int row = unit >> 3, c8 = (unit & 7) * 8;
        *(uint4*)&B2[row * 72 + c8] = *(const uint4*)(Wpost2 + (size_t)row * 64 + c8);
    }
    __syncthreads();

    f32x4 zero = {0.f, 0.f, 0.f, 0.f};
    f32x4 acc1[4];
    #pragma unroll
    for (int nt = 0; nt < 4; ++nt) acc1[nt] = zero;

    #pragma unroll
    for (int ks = 0; ks < 192; ks += 32) {
        bf16x8 a = *(const bf16x8*)&A1[(wv * 16 + l15) * 200 + ks + lhi * 8];
        #pragma unroll
        for (int nt = 0; nt < 4; ++nt) {
            bf16x8 bb = *(const bf16x8*)&B1[(nt * 16 + l15) * 200 + ks + lhi * 8];
            acc1[nt] = __builtin_amdgcn_mfma_f32_16x16x32_bf16(a, bb, acc1[nt], 0, 0, 0);
        }
    }
    __syncthreads();

    #pragma unroll
    for (int nt = 0; nt < 4; ++nt) {
        int col = nt * 16 + l15;
        float bcv = bcP[col];
        #pragma unroll
        for (int reg = 0; reg < 4; ++reg) {
            int row = wv * 16 + lhi * 4 + reg;
            A1[row * 72 + col] = f2bf(acc1[nt][reg] + bcv);
        }
    }
    __syncthreads();

    f32x4 acc2[4];
    #pragma unroll
    for (int nt = 0; nt < 4; ++nt) acc2[nt] = zero;
    #pragma unroll
    for (int ks = 0; ks < 64; ks += 32) {
        bf16x8 a = *(const bf16x8*)&A1[(wv * 16 + l15) * 72 + ks + lhi * 8];
        #pragma unroll
        for (int nt = 0; nt < 4; ++nt) {
            bf16x8 bb = *(const bf16x8*)&B2[(nt * 16 + l15) * 72 + ks + lhi * 8];
            acc2[nt] = __builtin_amdgcn_mfma_f32_16x16x32_bf16(a, bb, acc2[nt], 0, 0, 0);
        }
    }

    float biR[4];
    #pragma unroll
    for (int nt = 0; nt < 4; ++nt) biR[nt] = biP[nt * 16 + l15];

    #pragma unroll
    for (int reg = 0; reg < 4; ++reg) {
        size_t rowg = (size_t)blk * 64 + wv * 16 + lhi * 4 + reg;
        float esum = 0.f, dsum = 0.f;
        #pragma unroll
        for (int nt = 0; nt < 4; ++nt) {
            int col = nt * 16 + l15;
            if (col < 59) {
                float imp = acc2[nt][reg] + biR[nt];
                float v = values[rowg * 59 + col];
                float m = masks [rowg * 59 + col];
                out[rowg * 59 + col] = m * v + (1.f - m) * imp;
                esum += fabsf(v - imp) * m;
                dsum += m;
            }
        }
        #pragma unroll
        for (int o = 1; o < 16; o <<= 1) {
            esum += __shfl_xor(esum, o);
            dsum += __shfl_xor(dsum, o);
        }
        if (l15 == 0) { pnum[rowg] = esum; pden[rowg] = dsum; }
    }
}

// ---------------------------------------------------------------------------
// loss reduction (parallel): block t sums over b, atomicAdd num/(den+eps)
// ---------------------------------------------------------------------------
__global__ __launch_bounds__(256)
void loss_kernel(const float* __restrict__ pnum, const float* __restrict__ pden,
                 float* __restrict__ out)
{
    __shared__ float sn[4], sd[4];
    const int t = blockIdx.x;              // 0..127
    const int tid = threadIdx.x;
    float a = 0.f, b = 0.f;
    for (int bb = tid; bb < 512; bb += 256) {
        a += pnum[(size_t)bb * 128 + t];
        b += pden[(size_t)bb * 128 + t];
    }
    #pragma unroll
    for (int o = 32; o >= 1; o >>= 1) {
        a += __shfl_xor(a, o);
        b += __shfl_xor(b, o);
    }
    const int wv = tid >> 6;
    if ((tid & 63) == 0) { sn[wv] = a; sd[wv] = b; }
    __syncthreads();
    if (tid == 0) {
        float A = sn[0] + sn[1] + sn[2] + sn[3];
        float B = sd[0] + sd[1] + sd[2] + sd[3];
        atomicAdd(out + 3866624, A / (B + 1e-5f));   // B*T*V slot, zeroed by prep
    }
}

// ---------------------------------------------------------------------------
extern "C" void kernel_launch(void* const* d_in, const int* in_sizes, int n_in,
                              void* d_out, int out_size, void* d_ws, size_t ws_size,
                              hipStream_t stream)
{
    const float* values   = (const float*)d_in[0];
    const float* masks    = (const float*)d_in[1];
    const float* deltas_f = (const float*)d_in[2];
    const float* deltas_b = (const float*)d_in[3];
    const float* Wih = (const float*)d_in[4];
    const float* Whh = (const float*)d_in[5];
    const float* bih = (const float*)d_in[6];
    const float* bhh = (const float*)d_in[7];
    const float* Wh  = (const float*)d_in[8];
    const float* bh  = (const float*)d_in[9];
    const float* Wf  = (const float*)d_in[10];
    const float* bf_ = (const float*)d_in[11];
    const float* Wc  = (const float*)d_in[12];
    const float* bc  = (const float*)d_in[13];
    const float* Wi  = (const float*)d_in[14];
    const float* bi  = (const float*)d_in[15];
    float* out = (float*)d_out;

    uint8_t* ws = (uint8_t*)d_ws;
    size_t off = 0;
    auto alloc = [&](size_t bytes) -> void* {
        void* p = ws + off;
        off = (off + bytes + 255) & ~((size_t)255);
        return p;
    };
    ushort_t* xcat_f = (ushort_t*)alloc(128ULL * 512 * 192 * 2);
    ushort_t* xcat_b = (ushort_t*)alloc(128ULL * 512 * 192 * 2);
    ushort_t* WhhB   = (ushort_t*)alloc(1536ULL * 512 * 2);
    ushort_t* WihB   = (ushort_t*)alloc(1536ULL * 192 * 2);
    ushort_t* WhpB   = (ushort_t*)alloc(64ULL * 1024 * 2);
    ushort_t* hfS    = (ushort_t*)alloc(128ULL * 512 * 512 * 2);
    ushort_t* hbS    = (ushort_t*)alloc(128ULL * 512 * 512 * 2);
    float*    hstate = (float*)alloc(1024ULL * 512 * 4);
    ushort_t* pcat   = (ushort_t*)alloc(65536ULL * 192 * 2);
    ushort_t* Wpost1 = (ushort_t*)alloc(64ULL * 192 * 2);
    ushort_t* Wpost2 = (ushort_t*)alloc(64ULL * 64 * 2);
    float*    bcP    = (float*)alloc(64 * 4);
    float*    biP    = (float*)alloc(64 * 4);
    float*    pnum   = (float*)alloc(65536ULL * 4);
    float*    pden   = (float*)alloc(65536ULL * 4);
    unsigned* bar    = (unsigned*)alloc(16ULL * 16 * 32 * 4);   // 32 KB slots

    prep_small<<<1024, 256, 0, stream>>>(Wih, Whh, Wh, Wf, bf_, Wc, bc, Wi, bi,
                                         WhhB, WihB, WhpB, hfS, hbS, hstate,
                                         Wpost1, Wpost2, bcP, biP, bar, out);
    prep_panels<<<65536, 192, 0, stream>>>(values, masks, deltas_f, deltas_b,
                                           xcat_f, xcat_b, pcat);

    // Persistent recurrence (per-group barriers); fallback: 127 step launches
    const unsigned smemBytes = (96u * 704u + 2u * 64u * 64u) * 2u;  // 151552 B
    hipError_t aerr = hipFuncSetAttribute((const void*)recurrence_kernel,
                                          hipFuncAttributeMaxDynamicSharedMemorySize,
                                          (int)smemBytes);
    hipError_t lerr = hipErrorUnknown;
    if (aerr == hipSuccess) {
        const ushort_t* a0 = WhhB; const ushort_t* a1 = WihB;
        const float* a2 = bih; const float* a3 = bhh;
        const ushort_t* a4 = xcat_f; const ushort_t* a5 = xcat_b;
        ushort_t* a6 = hfS; ushort_t* a7 = hbS;
        unsigned* a8 = bar;
        void* args[] = { &a0, &a1, &a2, &a3, &a4, &a5, &a6, &a7, &a8 };
        lerr = hipLaunchCooperativeKernel((const void*)recurrence_kernel,
                                          dim3(256), dim3(512), args, smemBytes, stream);
    }
    if (lerr != hipSuccess) {
        for (int t = 0; t < 127; ++t) {
            step_kernel<<<dim3(16, 16), 512, 0, stream>>>(
                hfS + (size_t)t * 512 * 512, hbS + (size_t)t * 512 * 512,
                hfS + (size_t)(t + 1) * 512 * 512, hbS + (size_t)(t + 1) * 512 * 512,
                xcat_f + (size_t)t * 512 * 192, xcat_b + (size_t)t * 512 * 192,
                WhhB, WihB, bih, bhh, hstate);
        }
    }

    xv_kernel<<<512, 256, 0, stream>>>(hfS, hbS, WhpB, bh, pcat);
    post_kernel<<<1024, 256, 0, stream>>>(pcat, Wpost1, Wpost2, bcP, biP,
                                          values, masks, out, pnum, pden);
    loss_kernel<<<128, 256, 0, stream>>>(pnum, pden, out);
}